// Round 5
// baseline (737.770 us; speedup 1.0000x reference)
//
#include <hip/hip_runtime.h>
#include <hip/hip_bf16.h>

typedef __bf16 bf16;
typedef __bf16 bf16x8 __attribute__((ext_vector_type(8)));
typedef float  f32x4  __attribute__((ext_vector_type(4)));

static __device__ __forceinline__ float b2f(bf16 x) { return (float)x; }
static __device__ __forceinline__ bf16  f2b(float x) { return (bf16)x; }
static __device__ __forceinline__ float ldval(float v) { return v; }
static __device__ __forceinline__ float ldval(bf16 v)  { return (float)v; }

// async global->LDS, 16B per lane; lds dest must be wave-uniform base (+lane*16)
static __device__ __forceinline__ void gl_lds16(const bf16* g, bf16* l)
{
    __builtin_amdgcn_global_load_lds(
        (const __attribute__((address_space(1))) void*)g,
        (__attribute__((address_space(3))) void*)l,
        16, 0, 0);
}

// ---------------------------------------------------------------------------
// dtype detection: true-bf16 N(0,1) data never has exponent field >= 0xE0;
// f32 data read as bf16 half-words has ~12.5% of low halves there. flag=1 -> f32.
// ---------------------------------------------------------------------------
__global__ void detect_dtype(const unsigned short* __restrict__ p, int* __restrict__ flag)
{
    if (threadIdx.x == 0 && blockIdx.x == 0) {
        int big = 0;
        for (int i = 0; i < 512; ++i) {
            int e = (p[i] >> 7) & 0xFF;
            if (e >= 0xE0) big++;
        }
        *flag = (big > 0) ? 1 : 0;
    }
}

// grid-stride conversion of one tensor to canonical bf16
__global__ __launch_bounds__(256) void convert_bf16(
    const void* __restrict__ src, bf16* __restrict__ dst, int n,
    const int* __restrict__ flag)
{
    int f = *flag;
    for (int i = blockIdx.x * 256 + threadIdx.x; i < n; i += gridDim.x * 256) {
        float v = f ? ((const float*)src)[i] : (float)((const bf16*)src)[i];
        dst[i] = f2b(v);
    }
}

struct VecPack { const void* src[14]; int n[14]; };
// one block per small vector; dst slot stride 4096 elements
__global__ __launch_bounds__(256) void convert_vecs(
    VecPack vp, bf16* __restrict__ dst, const int* __restrict__ flag)
{
    int v = blockIdx.x;
    int f = *flag;
    const void* s = vp.src[v];
    int n = vp.n[v];
    bf16* d = dst + (size_t)v * 4096;
    for (int i = threadIdx.x; i < n; i += 256) {
        float x = f ? ((const float*)s)[i] : (float)((const bf16*)s)[i];
        d[i] = f2b(x);
    }
}

// ---------------------------------------------------------------------------
// GEMM: C[M,N] = A[M,K] @ B[K,N], with B supplied TRANSPOSED: Bt[n][k] (ld=ldb).
// 128x128 tile, BK=64, 256 threads = 4 waves, each wave a 64x64 quadrant of
// 4x4 mfma_f32_16x16x32_bf16 tiles. Staging via global_load_lds width=16
// (LDS unpadded: dest is wave-uniform base + lane*16).
// EPI: 0 = f32 store (+bias)   1 = bf16 store of v*scale
//      2 = bf16 gelu(v+bias)   3 = f32 store (v+bias+resid)  [final output]
// ---------------------------------------------------------------------------
template <int EPI>
__global__ __launch_bounds__(256) void gemm_bt(
    const bf16* __restrict__ A0, int lda, int zsA,
    const bf16* __restrict__ B0, int ldb, int zsB,
    void* __restrict__ C0, int ldc, int zsC,
    const bf16* __restrict__ bias, const bf16* __restrict__ resid,
    float scale, int K)
{
    __shared__ __align__(16) bf16 As[128][64];   // unpadded: global_load_lds layout
    __shared__ __align__(16) bf16 Bs[128][64];
    const int z = blockIdx.z;
    const bf16* A  = A0 + (size_t)z * zsA;
    const bf16* Bt = B0 + (size_t)z * zsB;
    const int tid  = threadIdx.x;
    const int lane = tid & 63, wave = tid >> 6;
    const int quad = lane >> 4, l16 = lane & 15;
    const size_t tm = (size_t)blockIdx.y * 128, tn = (size_t)blockIdx.x * 128;
    const int wm = (wave >> 1) * 64, wn = (wave & 1) * 64;
    const int srow = (lane >> 3);            // staging row-within-chunk
    const int scol = (lane & 7) * 8;         // staging col (elements)

    f32x4 acc[4][4];
    const f32x4 zro = {0.f, 0.f, 0.f, 0.f};
    #pragma unroll
    for (int i = 0; i < 4; ++i)
        #pragma unroll
        for (int j = 0; j < 4; ++j) acc[i][j] = zro;

    for (int k0 = 0; k0 < K; k0 += 64) {
        #pragma unroll
        for (int i = 0; i < 4; ++i) {
            int chunk = wave * 4 + i;        // 16 chunks x 1KiB per operand
            int row = chunk * 8 + srow;
            gl_lds16(A + (tm + row) * (size_t)lda + k0 + scol, &As[0][0] + chunk * 512);
            gl_lds16(Bt + (tn + row) * (size_t)ldb + k0 + scol, &Bs[0][0] + chunk * 512);
        }
        __syncthreads();
        #pragma unroll
        for (int kk = 0; kk < 2; ++kk) {
            bf16x8 af[4], bfr[4];
            #pragma unroll
            for (int i = 0; i < 4; ++i)
                af[i] = *(const bf16x8*)(const void*)&As[wm + i*16 + l16][kk*32 + quad*8];
            #pragma unroll
            for (int j = 0; j < 4; ++j)
                bfr[j] = *(const bf16x8*)(const void*)&Bs[wn + j*16 + l16][kk*32 + quad*8];
            #pragma unroll
            for (int i = 0; i < 4; ++i)
                #pragma unroll
                for (int j = 0; j < 4; ++j)
                    acc[i][j] = __builtin_amdgcn_mfma_f32_16x16x32_bf16(
                        af[i], bfr[j], acc[i][j], 0, 0, 0);
        }
        __syncthreads();
    }

    float* Cf = (float*)C0;
    bf16*  Cb = (bf16*)C0;
    #pragma unroll
    for (int i = 0; i < 4; ++i) {
        #pragma unroll
        for (int j = 0; j < 4; ++j) {
            size_t col = tn + wn + j*16 + l16;
            float bb = bias ? b2f(bias[col]) : 0.f;
            #pragma unroll
            for (int r = 0; r < 4; ++r) {
                size_t row = tm + wm + i*16 + quad*4 + r;
                float v = acc[i][j][r] + bb;
                size_t off = (size_t)z * zsC + row * (size_t)ldc + col;
                if (EPI == 0) {
                    Cf[off] = v;
                } else if (EPI == 1) {
                    Cb[off] = f2b(v * scale);
                } else if (EPI == 2) {
                    float g = 0.5f * v * (1.f + tanhf(0.7978845608028654f *
                                  (v + 0.044715f * v * v * v)));
                    Cb[off] = f2b(g);
                } else {
                    Cf[off] = v + b2f(resid[row * (size_t)ldc + col]);
                }
            }
        }
    }
}

// ---------------------------------------------------------------------------
// bf16 transpose (canonical bf16 input): out[c*ldo + off + r] = in[r*C + c]
// ---------------------------------------------------------------------------
__global__ void transpose_b16(const unsigned short* __restrict__ in, int R, int C,
                              unsigned short* __restrict__ out, int ldo, int off)
{
    __shared__ unsigned short t[32][33];
    int c0 = blockIdx.x * 32, r0 = blockIdx.y * 32;
    int tx = threadIdx.x, ty = threadIdx.y;
    for (int i = ty; i < 32; i += 8)
        t[i][tx] = in[(size_t)(r0 + i) * C + c0 + tx];
    __syncthreads();
    for (int i = ty; i < 32; i += 8)
        out[(size_t)(c0 + i) * ldo + off + r0 + tx] = t[tx][i];
}

// dtype-branching transpose for raw weight inputs -> bf16 transposed
__global__ void transpose_any(const void* __restrict__ in, int R, int C,
                              unsigned short* __restrict__ out, int ldo,
                              const int* __restrict__ flag)
{
    __shared__ unsigned short t[32][33];
    int f = *flag;
    int c0 = blockIdx.x * 32, r0 = blockIdx.y * 32;
    int tx = threadIdx.x, ty = threadIdx.y;
    for (int i = ty; i < 32; i += 8) {
        size_t idx = (size_t)(r0 + i) * C + c0 + tx;
        bf16 v = f ? f2b(((const float*)in)[idx]) : ((const bf16*)in)[idx];
        t[i][tx] = *(unsigned short*)&v;
    }
    __syncthreads();
    for (int i = ty; i < 32; i += 8)
        out[(size_t)(c0 + i) * ldo + r0 + tx] = t[tx][i];
}

// ---------------------------------------------------------------------------
// V transpose into per-head Vt[bh][64][2048] bf16 (B-operand [n=d][k=key]).
// ---------------------------------------------------------------------------
__global__ void transpose_v(const float* __restrict__ qkv, bf16* __restrict__ Vt)
{
    __shared__ float t[32][33];
    int bh = blockIdx.z, b = bh >> 3, h = bh & 7;
    const float* src = qkv + (size_t)b * 2048 * 1536 + 1024 + h * 64;
    int c0 = blockIdx.x * 32, r0 = blockIdx.y * 32;   // c: d, r: token
    int tx = threadIdx.x, ty = threadIdx.y;
    for (int i = ty; i < 32; i += 8)
        t[i][tx] = src[(size_t)(r0 + i) * 1536 + c0 + tx];
    __syncthreads();
    bf16* dst = Vt + (size_t)bh * 64 * 2048;
    for (int i = ty; i < 32; i += 8)
        dst[(size_t)(c0 + i) * 2048 + r0 + tx] = f2b(t[tx][i]);
}

// ---------------------------------------------------------------------------
// Row LayerNorm: one block (256 thr) per row.
// ---------------------------------------------------------------------------
template <typename Tin>
__global__ __launch_bounds__(256) void ln_rows(
    const Tin* __restrict__ in, int C,
    const bf16* __restrict__ g, const bf16* __restrict__ b,
    bf16* __restrict__ out, float eps)
{
    const int row = blockIdx.x, tid = threadIdx.x;
    const Tin* p = in + (size_t)row * C;
    float s = 0.f, ss = 0.f;
    for (int c = tid; c < C; c += 256) {
        float v = ldval(p[c]);
        s += v; ss += v * v;
    }
    #pragma unroll
    for (int d = 32; d > 0; d >>= 1) { s += __shfl_xor(s, d); ss += __shfl_xor(ss, d); }
    __shared__ float red[2][4];
    int wave = tid >> 6, lane = tid & 63;
    if (lane == 0) { red[0][wave] = s; red[1][wave] = ss; }
    __syncthreads();
    s  = red[0][0] + red[0][1] + red[0][2] + red[0][3];
    ss = red[1][0] + red[1][1] + red[1][2] + red[1][3];
    float mu   = s / C;
    float var  = ss / C - mu * mu;
    float rstd = rsqrtf(var + eps);
    bf16* q = out + (size_t)row * C;
    for (int c = tid; c < C; c += 256) {
        float v = ldval(p[c]);
        q[c] = f2b((v - mu) * rstd * b2f(g[c]) + b2f(b[c]));
    }
}

// ---------------------------------------------------------------------------
// Rotary: qrot = rope(text)*DIM^-0.5 ; krotPad[b][512+t] = rope(audio_t).
// ---------------------------------------------------------------------------
__global__ __launch_bounds__(256) void rotary_kernel(
    const bf16* __restrict__ text, const bf16* __restrict__ audioT,
    bf16* __restrict__ qrot, bf16* __restrict__ krotPad)
{
    int row = blockIdx.x;              // b*2048 + t
    int t = row & 2047, b = row >> 11;
    int tid = threadIdx.x;
    const float lg = 9.210340371976184f / 512.f;   // ln(10000)/512
    size_t base = (size_t)row * 1024;
    size_t kb = ((size_t)(b * 2560 + 512 + t)) * 1024;
    for (int c = tid; c < 512; c += 256) {
        float invf = __expf(-(float)c * lg);
        float th = (float)t * invf;
        float sn, cs;
        sincosf(th, &sn, &cs);
        float q1 = b2f(text[base + c]), q2 = b2f(text[base + c + 512]);
        qrot[base + c]       = f2b((q1 * cs - q2 * sn) * 0.03125f);
        qrot[base + c + 512] = f2b((q2 * cs + q1 * sn) * 0.03125f);
        float k1 = b2f(audioT[base + c]), k2 = b2f(audioT[base + c + 512]);
        krotPad[kb + c]       = f2b(k1 * cs - k2 * sn);
        krotPad[kb + c + 512] = f2b(k2 * cs + k1 * sn);
    }
}

// ---------------------------------------------------------------------------
// Local-attention masked softmax. sim [b][w][512][1024] f32 -> attn bf16.
// ---------------------------------------------------------------------------
__global__ __launch_bounds__(256) void softmax_local(
    const float* __restrict__ sim, bf16* __restrict__ attn)
{
    int i  = blockIdx.x;
    int zz = blockIdx.y;        // b*4 + w
    int w  = zz & 3;
    int tid = threadIdx.x;
    const float* p = sim + ((size_t)zz * 512 + i) * 1024;
    bf16* q = attn + ((size_t)zz * 512 + i) * 1024;
    int jlo = (w == 0) ? 512 : 0;
    int jhi = 512 + i;
    float m = -1e30f;
    #pragma unroll
    for (int k = 0; k < 4; ++k) {
        int c = tid + k * 256;
        if (c >= jlo && c <= jhi) m = fmaxf(m, p[c]);
    }
    #pragma unroll
    for (int d = 32; d > 0; d >>= 1) m = fmaxf(m, __shfl_xor(m, d));
    __shared__ float red[2][4];
    int wave = tid >> 6, lane = tid & 63;
    if (lane == 0) red[0][wave] = m;
    __syncthreads();
    m = fmaxf(fmaxf(red[0][0], red[0][1]), fmaxf(red[0][2], red[0][3]));
    float pv[4];
    float s = 0.f;
    #pragma unroll
    for (int k = 0; k < 4; ++k) {
        int c = tid + k * 256;
        float e = (c >= jlo && c <= jhi) ? __expf(p[c] - m) : 0.f;
        pv[k] = e; s += e;
    }
    #pragma unroll
    for (int d = 32; d > 0; d >>= 1) s += __shfl_xor(s, d);
    if (lane == 0) red[1][wave] = s;
    __syncthreads();
    s = red[1][0] + red[1][1] + red[1][2] + red[1][3];
    float inv = 1.f / s;
    #pragma unroll
    for (int k = 0; k < 4; ++k) q[tid + k * 256] = f2b(pv[k] * inv);
}

// ---------------------------------------------------------------------------
// pack_qk: per-(token,head) RMSNorm of q/k from qkv f32 [4096][1536], packed
// to per-head bf16 Qp/Kp[bh][2048][64]. Q gets the exact *0.125 scale folded.
// ---------------------------------------------------------------------------
__global__ __launch_bounds__(256) void pack_qk(
    const float* __restrict__ qkv, bf16* __restrict__ Qp, bf16* __restrict__ Kp,
    const bf16* __restrict__ qn_g, const bf16* __restrict__ kn_g)
{
    int gid  = blockIdx.x * 4 + (threadIdx.x >> 6);
    int lane = threadIdx.x & 63;
    int token = gid >> 4, r = gid & 15, part = r >> 3, h = r & 7;
    const float* p = qkv + (size_t)token * 1536 + part * 512 + h * 64 + lane;
    float v = *p;
    float ss = v * v;
    #pragma unroll
    for (int d = 32; d > 0; d >>= 1) ss += __shfl_xor(ss, d);
    float sc = rsqrtf(ss * (1.f / 64.f) + 1e-6f);
    const bf16* gw = part ? kn_g : qn_g;
    float outv = v * sc * b2f(gw[lane]);
    if (!part) outv *= 0.125f;                      // DHEAD^-0.5 (exact pow2)
    int b = token >> 11, t = token & 2047;
    bf16* dst = (part ? Kp : Qp) + ((size_t)(b * 8 + h) * 2048 + t) * 64 + lane;
    *dst = f2b(outv);
}

// ---------------------------------------------------------------------------
// MFMA flash attention (causal, D=64). Grid (32 q-blocks, 16 bh), 256 thr.
// ---------------------------------------------------------------------------
__global__ __launch_bounds__(256) void flash_mfma(
    const bf16* __restrict__ Qp, const bf16* __restrict__ Kp,
    const bf16* __restrict__ Vt, bf16* __restrict__ o)
{
    __shared__ __align__(16) bf16 Ks[64][72];       // [key][d]
    __shared__ __align__(16) bf16 Vs[64][72];       // [d][key]
    __shared__ __align__(16) bf16 Ps[4][16][72];    // per-wave P [qrow][key]
    const int bh = blockIdx.y, b = bh >> 3, h = bh & 7;
    const int qm = (31 - (int)blockIdx.x) * 64;     // long rows first
    const int tid = threadIdx.x, wave = tid >> 6, lane = tid & 63;
    const int quad = lane >> 4, l16 = lane & 15;
    const bf16* Qg = Qp + (size_t)bh * 2048 * 64;
    const bf16* Kg = Kp + (size_t)bh * 2048 * 64;
    const bf16* Vg = Vt + (size_t)bh * 64 * 2048;

    const int qrow = qm + wave * 16 + l16;
    bf16x8 qa[2];
    qa[0] = *(const bf16x8*)(const void*)(Qg + (size_t)qrow * 64 + quad * 8);
    qa[1] = *(const bf16x8*)(const void*)(Qg + (size_t)qrow * 64 + 32 + quad * 8);

    f32x4 oacc[4];
    const f32x4 zro = {0.f, 0.f, 0.f, 0.f};
    #pragma unroll
    for (int j = 0; j < 4; ++j) oacc[j] = zro;
    float mst[4] = {-1e30f, -1e30f, -1e30f, -1e30f};
    float lst[4] = {0.f, 0.f, 0.f, 0.f};

    const int ldr = tid >> 2, ldc = (tid & 3) * 16;
    for (int jt = 0; jt <= qm; jt += 64) {
        *(uint4*)(void*)&Ks[ldr][ldc] =
            *(const uint4*)(const void*)(Kg + (size_t)(jt + ldr) * 64 + ldc);
        *(uint4*)(void*)&Ks[ldr][ldc + 8] =
            *(const uint4*)(const void*)(Kg + (size_t)(jt + ldr) * 64 + ldc + 8);
        *(uint4*)(void*)&Vs[ldr][ldc] =
            *(const uint4*)(const void*)(Vg + (size_t)ldr * 2048 + jt + ldc);
        *(uint4*)(void*)&Vs[ldr][ldc + 8] =
            *(const uint4*)(const void*)(Vg + (size_t)ldr * 2048 + jt + ldc + 8);
        __syncthreads();

        f32x4 s[4];
        #pragma unroll
        for (int j = 0; j < 4; ++j) s[j] = zro;
        #pragma unroll
        for (int kk = 0; kk < 2; ++kk) {
            #pragma unroll
            for (int j = 0; j < 4; ++j) {
                bf16x8 kb = *(const bf16x8*)(const void*)&Ks[j*16 + l16][kk*32 + quad*8];
                s[j] = __builtin_amdgcn_mfma_f32_16x16x32_bf16(qa[kk], kb, s[j], 0, 0, 0);
            }
        }

        if (jt + 63 > qm + wave * 16) {
            #pragma unroll
            for (int j = 0; j < 4; ++j) {
                int key = jt + j * 16 + l16;
                #pragma unroll
                for (int r = 0; r < 4; ++r) {
                    int row = qm + wave * 16 + quad * 4 + r;
                    if (key > row) s[j][r] = -1e30f;
                }
            }
        }

        f32x4 tmax = s[0];
        #pragma unroll
        for (int j = 1; j < 4; ++j)
            #pragma unroll
            for (int r = 0; r < 4; ++r) tmax[r] = fmaxf(tmax[r], s[j][r]);
        #pragma unroll
        for (int r = 0; r < 4; ++r) {
            float tv = tmax[r];
            #pragma unroll
            for (int d = 1; d < 16; d <<= 1) tv = fmaxf(tv, __shfl_xor(tv, d));
            tmax[r] = tv;
        }
        float scl[4];
        #pragma unroll
        for (int r = 0; r < 4; ++r) {
            float mn = fmaxf(mst[r], tmax[r]);
            scl[r] = __expf(mst[r] - mn);
            mst[r] = mn;
        }
        f32x4 psum = zro;
        #pragma unroll
        for (int j = 0; j < 4; ++j)
            #pragma unroll
            for (int r = 0; r < 4; ++r) {
                float e = __expf(s[j][r] - mst[r]);
                s[j][r] = e;
                psum[r] += e;
            }
        #pragma unroll
        for (int r = 0; r < 4; ++r) {
            float tv = psum[r];
            #pragma unroll
            for (int d = 1; d < 16; d <<= 1) tv += __shfl_xor(tv, d);
            lst[r] = lst[r] * scl[r] + tv;
        }
        #pragma unroll
        for (int j = 0; j < 4; ++j)
            #pragma unroll
            for (int r = 0; r < 4; ++r) oacc[j][r] *= scl[r];

        #pragma unroll
        for (int j = 0; j < 4; ++j)
            #pragma unroll
            for (int r = 0; r < 4; ++r)
                Ps[wave][quad*4 + r][j*16 + l16] = f2b(s[j][r]);
        bf16x8 pa[2];
        pa[0] = *(const bf16x8*)(const void*)&Ps[wave][l16][quad*8];
        pa[1] = *(const bf16x8*)(const void*)&Ps[wave][l16][32 + quad*8];

        #pragma unroll
        for (int kk = 0; kk < 2; ++kk) {
            #pragma unroll
            for (int j = 0; j < 4; ++j) {
                bf16x8 vb = *(const bf16x8*)(const void*)&Vs[j*16 + l16][kk*32 + quad*8];
                oacc[j] = __builtin_amdgcn_mfma_f32_16x16x32_bf16(pa[kk], vb, oacc[j], 0, 0, 0);
            }
        }
        __syncthreads();
    }

    #pragma unroll
    for (int j = 0; j < 4; ++j) {
        #pragma unroll
        for (int r = 0; r < 4; ++r) {
            int t = qm + wave * 16 + quad * 4 + r;
            o[((size_t)(b * 2048 + t)) * 512 + h * 64 + j * 16 + l16] =
                f2b(oacc[j][r] / lst[r]);
        }
    }
}

// ---------------------------------------------------------------------------
static void launch_gemm(int epi, hipStream_t s,
                        const bf16* A, int lda, int zsA,
                        const bf16* Bt, int ldb, int zsB,
                        void* C, int ldc, int zsC,
                        const bf16* bias, const bf16* resid, float scale,
                        int M, int N, int K, int nz)
{
    dim3 g(N / 128, M / 128, nz), blk(256);
    switch (epi) {
    case 0: gemm_bt<0><<<g, blk, 0, s>>>(A, lda, zsA, Bt, ldb, zsB, C, ldc, zsC, bias, resid, scale, K); break;
    case 1: gemm_bt<1><<<g, blk, 0, s>>>(A, lda, zsA, Bt, ldb, zsB, C, ldc, zsC, bias, resid, scale, K); break;
    case 2: gemm_bt<2><<<g, blk, 0, s>>>(A, lda, zsA, Bt, ldb, zsB, C, ldc, zsC, bias, resid, scale, K); break;
    default: gemm_bt<3><<<g, blk, 0, s>>>(A, lda, zsA, Bt, ldb, zsB, C, ldc, zsC, bias, resid, scale, K); break;
    }
}

extern "C" void kernel_launch(void* const* d_in, const int* in_sizes, int n_in,
                              void* d_out, int out_size, void* d_ws, size_t ws_size,
                              hipStream_t stream)
{
    const void* text  = d_in[0];
    const void* audio = d_in[1];
    const void* video = d_in[2];
    const void* Wa    = d_in[3];
    const void* ba    = d_in[4];
    const void* lna_g = d_in[5];
    const void* lna_b = d_in[6];
    const void* Wvid  = d_in[7];
    const void* bvid  = d_in[8];
    const void* lnv_g = d_in[9];
    const void* lnv_b = d_in[10];
    const void* ln1_g = d_in[11];
    const void* ln1_b = d_in[12];
    const void* Wq    = d_in[13];
    const void* Wkv   = d_in[14];
    const void* qn_g  = d_in[15];
    const void* kn_g  = d_in[16];
    const void* Wo    = d_in[17];
    const void* W1    = d_in[18];
    const void* b1    = d_in[19];
    const void* ln2_g = d_in[20];
    const void* ln2_b = d_in[21];
    const void* W2    = d_in[22];
    const void* b2    = d_in[23];

    char* ws = (char*)d_ws;
    size_t off = 0;
    auto alloc = [&](size_t bytes) -> char* {
        char* p = ws + off;
        off += (bytes + 255) & ~(size_t)255;
        return p;
    };
    const size_t MB = 1024 * 1024;
    int*  flag  = (int*)alloc(256);
    bf16* vecs  = (bf16*)alloc(14 * 4096 * 2);
    bf16* WqkvT = (bf16*)alloc((size_t)1536 * 1024 * 2);
    bf16* WoT   = (bf16*)alloc((size_t)1024 * 512 * 2);
    bf16* W1T   = (bf16*)alloc((size_t)4096 * 1024 * 2);
    bf16* W2T   = (bf16*)alloc((size_t)1024 * 4096 * 2);
    char* regionIn = alloc(24 * MB);   // textC,audioC,videoC -> later qkvF f32
    char* region2  = alloc(32 * MB);   // tmpF,xF f32 -> later g bf16
    char* regionH  = alloc(8 * MB);    // audioT -> h
    char* regionX  = alloc(8 * MB);    // videoT -> x2
    char* regionO  = alloc(4 * MB);    // WaT,WvT -> o
    bf16* qrot    = (bf16*)alloc((size_t)4096 * 1024 * 2);
    bf16* krotPad = (bf16*)alloc((size_t)2 * 2560 * 1024 * 2);
    bf16* VTpad   = (bf16*)alloc((size_t)2 * 1024 * 2560 * 2);
    bf16* attn    = (bf16*)alloc((size_t)8 * 512 * 1024 * 2);

    bf16*  textC  = (bf16*)regionIn;
    bf16*  audioC = textC + (size_t)4096 * 1024;
    bf16*  videoC = textC + (size_t)2 * 4096 * 1024;
    float* qkvF   = (float*)regionIn;
    float* tmpF   = (float*)region2;
    float* xF     = (float*)(region2 + 16 * MB);
    bf16*  g      = (bf16*)region2;
    bf16*  audioT = (bf16*)regionH;
    bf16*  h      = (bf16*)regionH;
    bf16*  videoT = (bf16*)regionX;
    bf16*  x2     = (bf16*)regionX;
    bf16*  WaT    = (bf16*)regionO;
    bf16*  WvT    = WaT + (size_t)1024 * 1024;
    bf16*  o      = (bf16*)regionO;
    bf16*  Qp     = qrot;
    bf16*  Kp     = krotPad;
    bf16*  Vth    = attn;

    bf16* baC   = vecs + 0 * 4096;
    bf16* bvidC = vecs + 1 * 4096;
    bf16* lnagC = vecs + 2 * 4096;
    bf16* lnabC = vecs + 3 * 4096;
    bf16* lnvgC = vecs + 4 * 4096;
    bf16* lnvbC = vecs + 5 * 4096;
    bf16* ln1gC = vecs + 6 * 4096;
    bf16* ln1bC = vecs + 7 * 4096;
    bf16* qngC  = vecs + 8 * 4096;
    bf16* kngC  = vecs + 9 * 4096;
    bf16* b1C   = vecs + 10 * 4096;
    bf16* ln2gC = vecs + 11 * 4096;
    bf16* ln2bC = vecs + 12 * 4096;
    bf16* b2C   = vecs + 13 * 4096;

    // 1) dtype flag
    detect_dtype<<<1, 64, 0, stream>>>((const unsigned short*)text, flag);

    // 2) canonicalize big activations + small vectors
    const int NTOK = 4096 * 1024;
    convert_bf16<<<2048, 256, 0, stream>>>(text, textC, NTOK, flag);
    convert_bf16<<<2048, 256, 0, stream>>>(audio, audioC, NTOK, flag);
    convert_bf16<<<2048, 256, 0, stream>>>(video, videoC, NTOK, flag);
    VecPack vp;
    const void* vsrc[14] = {ba, bvid, lna_g, lna_b, lnv_g, lnv_b, ln1_g, ln1_b,
                            qn_g, kn_g, b1, ln2_g, ln2_b, b2};
    int vn[14] = {1024, 1024, 1024, 1024, 1024, 1024, 1024, 1024,
                  64, 64, 4096, 4096, 4096, 1024};
    for (int i = 0; i < 14; ++i) { vp.src[i] = vsrc[i]; vp.n[i] = vn[i]; }
    convert_vecs<<<14, 256, 0, stream>>>(vp, vecs, flag);

    // 3) weight transposes (dtype-branching): out[n][k] = W[k][n]
    dim3 tb(32, 8);
    transpose_any<<<dim3(32, 32), tb, 0, stream>>>(Wa, 1024, 1024, (unsigned short*)WaT, 1024, flag);
    transpose_any<<<dim3(32, 32), tb, 0, stream>>>(Wvid, 1024, 1024, (unsigned short*)WvT, 1024, flag);
    transpose_any<<<dim3(16, 32), tb, 0, stream>>>(Wq, 1024, 512, (unsigned short*)WqkvT, 1024, flag);
    transpose_any<<<dim3(32, 32), tb, 0, stream>>>(Wkv, 1024, 1024, (unsigned short*)(WqkvT + (size_t)512 * 1024), 1024, flag);
    transpose_any<<<dim3(32, 16), tb, 0, stream>>>(Wo, 512, 1024, (unsigned short*)WoT, 512, flag);
    transpose_any<<<dim3(128, 32), tb, 0, stream>>>(W1, 1024, 4096, (unsigned short*)W1T, 1024, flag);
    transpose_any<<<dim3(32, 128), tb, 0, stream>>>(W2, 4096, 1024, (unsigned short*)W2T, 4096, flag);

    // 4) adapters
    launch_gemm(0, stream, audioC, 1024, 0, WaT, 1024, 0, tmpF, 1024, 0, baC, nullptr, 1.f, 4096, 1024, 1024, 1);
    ln_rows<float><<<4096, 256, 0, stream>>>(tmpF, 1024, lnagC, lnabC, audioT, 1e-5f);
    launch_gemm(0, stream, videoC, 1024, 0, WvT, 1024, 0, tmpF, 1024, 0, bvidC, nullptr, 1.f, 4096, 1024, 1024, 1);
    ln_rows<float><<<4096, 256, 0, stream>>>(tmpF, 1024, lnvgC, lnvbC, videoT, 1e-5f);

    // 5) zero look-backward pads, rotary, padded-V transpose
    hipMemsetAsync(krotPad, 0, (size_t)2 * 2560 * 1024 * 2, stream);
    hipMemsetAsync(VTpad, 0, (size_t)2 * 1024 * 2560 * 2, stream);
    rotary_kernel<<<4096, 256, 0, stream>>>(textC, audioT, qrot, krotPad);
    for (int b = 0; b < 2; ++b)
        transpose_b16<<<dim3(32, 64), tb, 0, stream>>>(
            (const unsigned short*)(videoT + (size_t)b * 2048 * 1024), 2048, 1024,
            (unsigned short*)(VTpad + (size_t)b * 1024 * 2560), 2560, 512);

    // 6) local attention: sim -> softmax -> @V
    for (int b = 0; b < 2; ++b)
        launch_gemm(0, stream,
                    qrot + (size_t)b * 2048 * 1024, 1024, 512 * 1024,
                    krotPad + (size_t)b * 2560 * 1024, 1024, 512 * 1024,
                    tmpF + (size_t)b * 4 * 512 * 1024, 1024, 512 * 1024,
                    nullptr, nullptr, 1.f, 512, 1024, 1024, 4);
    softmax_local<<<dim3(512, 8), 256, 0, stream>>>(tmpF, attn);
    for (int b = 0; b < 2; ++b)
        launch_gemm(0, stream,
                    attn + (size_t)b * 4 * 512 * 1024, 1024, 512 * 1024,
                    VTpad + (size_t)b * 1024 * 2560, 2560, 512,
                    xF + (size_t)b * 2048 * 1024, 1024, 512 * 1024,
                    nullptr, nullptr, 1.f, 512, 1024, 1024, 4);

    // 7) ln1 -> qkv -> pack(rmsnorm) -> V transpose -> MFMA flash
    ln_rows<float><<<4096, 256, 0, stream>>>(xF, 1024, ln1gC, ln1bC, h, 1e-5f);
    launch_gemm(0, stream, h, 1024, 0, WqkvT, 1024, 0, qkvF, 1536, 0, nullptr, nullptr, 1.f, 4096, 1536, 1024, 1);
    pack_qk<<<16384, 256, 0, stream>>>(qkvF, Qp, Kp, qngC, kngC);
    transpose_v<<<dim3(2, 64, 16), tb, 0, stream>>>(qkvF, Vth);
    flash_mfma<<<dim3(32, 16), 256, 0, stream>>>(Qp, Kp, Vth, o);

    // 8) x2 = 2*(o@Wo) ; g = gelu(x2@W1+b1) ; ln2 ; out(f32) = g@W2 + b2 + x2
    launch_gemm(1, stream, o, 512, 0, WoT, 512, 0, x2, 1024, 0, nullptr, nullptr, 2.f, 4096, 1024, 512, 1);
    launch_gemm(2, stream, x2, 1024, 0, W1T, 1024, 0, g, 4096, 0, b1C, nullptr, 1.f, 4096, 4096, 1024, 1);
    ln_rows<bf16><<<4096, 256, 0, stream>>>(g, 4096, ln2gC, ln2bC, g, 1e-5f);
    launch_gemm(3, stream, g, 4096, 0, W2T, 4096, 0, d_out, 1024, 0, b2C, x2, 1.f, 4096, 1024, 4096, 1);

    (void)in_sizes; (void)n_in; (void)out_size; (void)ws_size;
}

// Round 6
// 660.616 us; speedup vs baseline: 1.1168x; 1.1168x over previous
//
#include <hip/hip_runtime.h>
#include <hip/hip_bf16.h>

typedef __bf16 bf16;
typedef __bf16 bf16x8 __attribute__((ext_vector_type(8)));
typedef float  f32x4  __attribute__((ext_vector_type(4)));

static __device__ __forceinline__ float b2f(bf16 x) { return (float)x; }
static __device__ __forceinline__ bf16  f2b(float x) { return (bf16)x; }
static __device__ __forceinline__ float ldval(float v) { return v; }
static __device__ __forceinline__ float ldval(bf16 v)  { return (float)v; }

// async global->LDS, 16B per lane; lds dest is wave-uniform base (+lane*16)
static __device__ __forceinline__ void gl_lds16(const bf16* g, bf16* l)
{
    __builtin_amdgcn_global_load_lds(
        (const __attribute__((address_space(1))) void*)g,
        (__attribute__((address_space(3))) void*)l,
        16, 0, 0);
}

// ---------------------------------------------------------------------------
// dtype detection: flag=1 -> f32 inputs.
// ---------------------------------------------------------------------------
__global__ void detect_dtype(const unsigned short* __restrict__ p, int* __restrict__ flag)
{
    if (threadIdx.x == 0 && blockIdx.x == 0) {
        int big = 0;
        for (int i = 0; i < 512; ++i) {
            int e = (p[i] >> 7) & 0xFF;
            if (e >= 0xE0) big++;
        }
        *flag = (big > 0) ? 1 : 0;
    }
}

__global__ __launch_bounds__(256) void convert_bf16(
    const void* __restrict__ src, bf16* __restrict__ dst, int n,
    const int* __restrict__ flag)
{
    int f = *flag;
    for (int i = blockIdx.x * 256 + threadIdx.x; i < n; i += gridDim.x * 256) {
        float v = f ? ((const float*)src)[i] : (float)((const bf16*)src)[i];
        dst[i] = f2b(v);
    }
}

struct VecPack { const void* src[14]; int n[14]; };
__global__ __launch_bounds__(256) void convert_vecs(
    VecPack vp, bf16* __restrict__ dst, const int* __restrict__ flag)
{
    int v = blockIdx.x;
    int f = *flag;
    const void* s = vp.src[v];
    int n = vp.n[v];
    bf16* d = dst + (size_t)v * 4096;
    for (int i = threadIdx.x; i < n; i += 256) {
        float x = f ? ((const float*)s)[i] : (float)((const bf16*)s)[i];
        d[i] = f2b(x);
    }
}

// ---------------------------------------------------------------------------
// GEMM: C[M,N] = A[M,K] @ Bt[n][k]. MT x 128 tile (MT=128 or 64), BK=64,
// 256 thr = 4 waves. Staging: global_load_lds w=16 into XOR-swizzled LDS:
// chunk (row r, c) at index r*8 + (c ^ (r&7))  -> staging src chunk for lane
// is (lane&7)^(lane>>3); frag reads hit all 8 bank groups 2x per quad (free).
// EPI: 0 = f32 store (+bias)   1 = bf16 store of v*scale
//      2 = bf16 gelu(v+bias)   3 = f32 store (v+bias+resid)
// ---------------------------------------------------------------------------
template <int EPI, int MT>
__global__ __launch_bounds__(256) void gemm_bt(
    const bf16* __restrict__ A0, int lda, int zsA,
    const bf16* __restrict__ B0, int ldb, int zsB,
    void* __restrict__ C0, int ldc, int zsC,
    const bf16* __restrict__ bias, const bf16* __restrict__ resid,
    float scale, int K)
{
    constexpr int IFR = MT / 32;                  // i-frags per wave
    __shared__ __align__(16) bf16 As[MT * 64];
    __shared__ __align__(16) bf16 Bs[128 * 64];
    const int z = blockIdx.z;
    const bf16* A  = A0 + (size_t)z * zsA;
    const bf16* Bt = B0 + (size_t)z * zsB;
    const int tid  = threadIdx.x;
    const int lane = tid & 63, wave = tid >> 6;
    const int quad = lane >> 4, l16 = lane & 15;
    const size_t tm = (size_t)blockIdx.y * MT, tn = (size_t)blockIdx.x * 128;
    const int wm = (wave >> 1) * (MT / 2), wn = (wave & 1) * 64;
    const int srow = lane >> 3;                   // staging row within 8-row group
    const int scol = ((lane & 7) ^ srow) * 8;     // swizzled source chunk col

    f32x4 acc[IFR][4];
    const f32x4 zro = {0.f, 0.f, 0.f, 0.f};
    #pragma unroll
    for (int i = 0; i < IFR; ++i)
        #pragma unroll
        for (int j = 0; j < 4; ++j) acc[i][j] = zro;

    const int swzA = l16 & 7;                     // row&7 for frag rows
    for (int k0 = 0; k0 < K; k0 += 64) {
        #pragma unroll
        for (int i = 0; i < IFR; ++i) {
            int chunk = (wave * IFR + i) * 64;    // 64 chunks per wave-op
            int row = (chunk >> 3) + srow;
            gl_lds16(A + (tm + row) * (size_t)lda + k0 + scol, As + (size_t)chunk * 8);
        }
        #pragma unroll
        for (int i = 0; i < 4; ++i) {
            int chunk = (wave * 4 + i) * 64;
            int row = (chunk >> 3) + srow;
            gl_lds16(Bt + (tn + row) * (size_t)ldb + k0 + scol, Bs + (size_t)chunk * 8);
        }
        __syncthreads();
        #pragma unroll
        for (int kk = 0; kk < 2; ++kk) {
            bf16x8 af[IFR], bfr[4];
            #pragma unroll
            for (int i = 0; i < IFR; ++i) {
                int row = wm + i * 16 + l16;
                af[i] = *(const bf16x8*)(const void*)&As[(row * 8 + ((kk*4 + quad) ^ swzA)) * 8];
            }
            #pragma unroll
            for (int j = 0; j < 4; ++j) {
                int row = wn + j * 16 + l16;
                bfr[j] = *(const bf16x8*)(const void*)&Bs[(row * 8 + ((kk*4 + quad) ^ swzA)) * 8];
            }
            #pragma unroll
            for (int i = 0; i < IFR; ++i)
                #pragma unroll
                for (int j = 0; j < 4; ++j)
                    acc[i][j] = __builtin_amdgcn_mfma_f32_16x16x32_bf16(
                        af[i], bfr[j], acc[i][j], 0, 0, 0);
        }
        __syncthreads();
    }

    float* Cf = (float*)C0;
    bf16*  Cb = (bf16*)C0;
    #pragma unroll
    for (int i = 0; i < IFR; ++i) {
        #pragma unroll
        for (int j = 0; j < 4; ++j) {
            size_t col = tn + wn + j*16 + l16;
            float bb = bias ? b2f(bias[col]) : 0.f;
            #pragma unroll
            for (int r = 0; r < 4; ++r) {
                size_t row = tm + wm + i*16 + quad*4 + r;
                float v = acc[i][j][r] + bb;
                size_t off = (size_t)z * zsC + row * (size_t)ldc + col;
                if (EPI == 0) {
                    Cf[off] = v;
                } else if (EPI == 1) {
                    Cb[off] = f2b(v * scale);
                } else if (EPI == 2) {
                    float g = 0.5f * v * (1.f + tanhf(0.7978845608028654f *
                                  (v + 0.044715f * v * v * v)));
                    Cb[off] = f2b(g);
                } else {
                    Cf[off] = v + b2f(resid[row * (size_t)ldc + col]);
                }
            }
        }
    }
}

// ---------------------------------------------------------------------------
// bf16 transpose: out[c*ldo + off + r] = in[r*C + c]
// ---------------------------------------------------------------------------
__global__ void transpose_b16(const unsigned short* __restrict__ in, int R, int C,
                              unsigned short* __restrict__ out, int ldo, int off)
{
    __shared__ unsigned short t[32][33];
    int c0 = blockIdx.x * 32, r0 = blockIdx.y * 32;
    int tx = threadIdx.x, ty = threadIdx.y;
    for (int i = ty; i < 32; i += 8)
        t[i][tx] = in[(size_t)(r0 + i) * C + c0 + tx];
    __syncthreads();
    for (int i = ty; i < 32; i += 8)
        out[(size_t)(c0 + i) * ldo + off + r0 + tx] = t[tx][i];
}

__global__ void transpose_any(const void* __restrict__ in, int R, int C,
                              unsigned short* __restrict__ out, int ldo,
                              const int* __restrict__ flag)
{
    __shared__ unsigned short t[32][33];
    int f = *flag;
    int c0 = blockIdx.x * 32, r0 = blockIdx.y * 32;
    int tx = threadIdx.x, ty = threadIdx.y;
    for (int i = ty; i < 32; i += 8) {
        size_t idx = (size_t)(r0 + i) * C + c0 + tx;
        bf16 v = f ? f2b(((const float*)in)[idx]) : ((const bf16*)in)[idx];
        t[i][tx] = *(unsigned short*)&v;
    }
    __syncthreads();
    for (int i = ty; i < 32; i += 8)
        out[(size_t)(c0 + i) * ldo + r0 + tx] = t[tx][i];
}

// ---------------------------------------------------------------------------
// V transpose into per-head Vt[bh][64][2048] bf16.
// ---------------------------------------------------------------------------
__global__ void transpose_v(const float* __restrict__ qkv, bf16* __restrict__ Vt)
{
    __shared__ float t[32][33];
    int bh = blockIdx.z, b = bh >> 3, h = bh & 7;
    const float* src = qkv + (size_t)b * 2048 * 1536 + 1024 + h * 64;
    int c0 = blockIdx.x * 32, r0 = blockIdx.y * 32;
    int tx = threadIdx.x, ty = threadIdx.y;
    for (int i = ty; i < 32; i += 8)
        t[i][tx] = src[(size_t)(r0 + i) * 1536 + c0 + tx];
    __syncthreads();
    bf16* dst = Vt + (size_t)bh * 64 * 2048;
    for (int i = ty; i < 32; i += 8)
        dst[(size_t)(c0 + i) * 2048 + r0 + tx] = f2b(t[tx][i]);
}

// ---------------------------------------------------------------------------
// Row LayerNorm: one block per row.
// ---------------------------------------------------------------------------
template <typename Tin>
__global__ __launch_bounds__(256) void ln_rows(
    const Tin* __restrict__ in, int C,
    const bf16* __restrict__ g, const bf16* __restrict__ b,
    bf16* __restrict__ out, float eps)
{
    const int row = blockIdx.x, tid = threadIdx.x;
    const Tin* p = in + (size_t)row * C;
    float s = 0.f, ss = 0.f;
    for (int c = tid; c < C; c += 256) {
        float v = ldval(p[c]);
        s += v; ss += v * v;
    }
    #pragma unroll
    for (int d = 32; d > 0; d >>= 1) { s += __shfl_xor(s, d); ss += __shfl_xor(ss, d); }
    __shared__ float red[2][4];
    int wave = tid >> 6, lane = tid & 63;
    if (lane == 0) { red[0][wave] = s; red[1][wave] = ss; }
    __syncthreads();
    s  = red[0][0] + red[0][1] + red[0][2] + red[0][3];
    ss = red[1][0] + red[1][1] + red[1][2] + red[1][3];
    float mu   = s / C;
    float var  = ss / C - mu * mu;
    float rstd = rsqrtf(var + eps);
    bf16* q = out + (size_t)row * C;
    for (int c = tid; c < C; c += 256) {
        float v = ldval(p[c]);
        q[c] = f2b((v - mu) * rstd * b2f(g[c]) + b2f(b[c]));
    }
}

// ---------------------------------------------------------------------------
// Rotary: qrot = rope(text)*DIM^-0.5 ; krotPad[b][512+t] = rope(audio_t).
// ---------------------------------------------------------------------------
__global__ __launch_bounds__(256) void rotary_kernel(
    const bf16* __restrict__ text, const bf16* __restrict__ audioT,
    bf16* __restrict__ qrot, bf16* __restrict__ krotPad)
{
    int row = blockIdx.x;
    int t = row & 2047, b = row >> 11;
    int tid = threadIdx.x;
    const float lg = 9.210340371976184f / 512.f;
    size_t base = (size_t)row * 1024;
    size_t kb = ((size_t)(b * 2560 + 512 + t)) * 1024;
    for (int c = tid; c < 512; c += 256) {
        float invf = __expf(-(float)c * lg);
        float th = (float)t * invf;
        float sn, cs;
        sincosf(th, &sn, &cs);
        float q1 = b2f(text[base + c]), q2 = b2f(text[base + c + 512]);
        qrot[base + c]       = f2b((q1 * cs - q2 * sn) * 0.03125f);
        qrot[base + c + 512] = f2b((q2 * cs + q1 * sn) * 0.03125f);
        float k1 = b2f(audioT[base + c]), k2 = b2f(audioT[base + c + 512]);
        krotPad[kb + c]       = f2b(k1 * cs - k2 * sn);
        krotPad[kb + c + 512] = f2b(k2 * cs + k1 * sn);
    }
}

// ---------------------------------------------------------------------------
// Local-attention masked softmax. sim [b][w][512][1024] f32 -> attn bf16.
// ---------------------------------------------------------------------------
__global__ __launch_bounds__(256) void softmax_local(
    const float* __restrict__ sim, bf16* __restrict__ attn)
{
    int i  = blockIdx.x;
    int zz = blockIdx.y;
    int w  = zz & 3;
    int tid = threadIdx.x;
    const float* p = sim + ((size_t)zz * 512 + i) * 1024;
    bf16* q = attn + ((size_t)zz * 512 + i) * 1024;
    int jlo = (w == 0) ? 512 : 0;
    int jhi = 512 + i;
    float m = -1e30f;
    #pragma unroll
    for (int k = 0; k < 4; ++k) {
        int c = tid + k * 256;
        if (c >= jlo && c <= jhi) m = fmaxf(m, p[c]);
    }
    #pragma unroll
    for (int d = 32; d > 0; d >>= 1) m = fmaxf(m, __shfl_xor(m, d));
    __shared__ float red[2][4];
    int wave = tid >> 6, lane = tid & 63;
    if (lane == 0) red[0][wave] = m;
    __syncthreads();
    m = fmaxf(fmaxf(red[0][0], red[0][1]), fmaxf(red[0][2], red[0][3]));
    float pv[4];
    float s = 0.f;
    #pragma unroll
    for (int k = 0; k < 4; ++k) {
        int c = tid + k * 256;
        float e = (c >= jlo && c <= jhi) ? __expf(p[c] - m) : 0.f;
        pv[k] = e; s += e;
    }
    #pragma unroll
    for (int d = 32; d > 0; d >>= 1) s += __shfl_xor(s, d);
    if (lane == 0) red[1][wave] = s;
    __syncthreads();
    s = red[1][0] + red[1][1] + red[1][2] + red[1][3];
    float inv = 1.f / s;
    #pragma unroll
    for (int k = 0; k < 4; ++k) q[tid + k * 256] = f2b(pv[k] * inv);
}

// ---------------------------------------------------------------------------
// pack_qk: RMSNorm q/k from qkv f32 [4096][1536] -> per-head bf16 buffers.
// ---------------------------------------------------------------------------
__global__ __launch_bounds__(256) void pack_qk(
    const float* __restrict__ qkv, bf16* __restrict__ Qp, bf16* __restrict__ Kp,
    const bf16* __restrict__ qn_g, const bf16* __restrict__ kn_g)
{
    int gid  = blockIdx.x * 4 + (threadIdx.x >> 6);
    int lane = threadIdx.x & 63;
    int token = gid >> 4, r = gid & 15, part = r >> 3, h = r & 7;
    const float* p = qkv + (size_t)token * 1536 + part * 512 + h * 64 + lane;
    float v = *p;
    float ss = v * v;
    #pragma unroll
    for (int d = 32; d > 0; d >>= 1) ss += __shfl_xor(ss, d);
    float sc = rsqrtf(ss * (1.f / 64.f) + 1e-6f);
    const bf16* gw = part ? kn_g : qn_g;
    float outv = v * sc * b2f(gw[lane]);
    if (!part) outv *= 0.125f;
    int b = token >> 11, t = token & 2047;
    bf16* dst = (part ? Kp : Qp) + ((size_t)(b * 8 + h) * 2048 + t) * 64 + lane;
    *dst = f2b(outv);
}

// ---------------------------------------------------------------------------
// MFMA flash attention (causal, D=64). Grid (32 q-blocks, 16 bh), 256 thr.
// ---------------------------------------------------------------------------
__global__ __launch_bounds__(256) void flash_mfma(
    const bf16* __restrict__ Qp, const bf16* __restrict__ Kp,
    const bf16* __restrict__ Vt, bf16* __restrict__ o)
{
    __shared__ __align__(16) bf16 Ks[64][72];
    __shared__ __align__(16) bf16 Vs[64][72];
    __shared__ __align__(16) bf16 Ps[4][16][72];
    const int bh = blockIdx.y, b = bh >> 3, h = bh & 7;
    const int qm = (31 - (int)blockIdx.x) * 64;
    const int tid = threadIdx.x, wave = tid >> 6, lane = tid & 63;
    const int quad = lane >> 4, l16 = lane & 15;
    const bf16* Qg = Qp + (size_t)bh * 2048 * 64;
    const bf16* Kg = Kp + (size_t)bh * 2048 * 64;
    const bf16* Vg = Vt + (size_t)bh * 64 * 2048;

    const int qrow = qm + wave * 16 + l16;
    bf16x8 qa[2];
    qa[0] = *(const bf16x8*)(const void*)(Qg + (size_t)qrow * 64 + quad * 8);
    qa[1] = *(const bf16x8*)(const void*)(Qg + (size_t)qrow * 64 + 32 + quad * 8);

    f32x4 oacc[4];
    const f32x4 zro = {0.f, 0.f, 0.f, 0.f};
    #pragma unroll
    for (int j = 0; j < 4; ++j) oacc[j] = zro;
    float mst[4] = {-1e30f, -1e30f, -1e30f, -1e30f};
    float lst[4] = {0.f, 0.f, 0.f, 0.f};

    const int ldr = tid >> 2, ldc = (tid & 3) * 16;
    for (int jt = 0; jt <= qm; jt += 64) {
        *(uint4*)(void*)&Ks[ldr][ldc] =
            *(const uint4*)(const void*)(Kg + (size_t)(jt + ldr) * 64 + ldc);
        *(uint4*)(void*)&Ks[ldr][ldc + 8] =
            *(const uint4*)(const void*)(Kg + (size_t)(jt + ldr) * 64 + ldc + 8);
        *(uint4*)(void*)&Vs[ldr][ldc] =
            *(const uint4*)(const void*)(Vg + (size_t)ldr * 2048 + jt + ldc);
        *(uint4*)(void*)&Vs[ldr][ldc + 8] =
            *(const uint4*)(const void*)(Vg + (size_t)ldr * 2048 + jt + ldc + 8);
        __syncthreads();

        f32x4 s[4];
        #pragma unroll
        for (int j = 0; j < 4; ++j) s[j] = zro;
        #pragma unroll
        for (int kk = 0; kk < 2; ++kk) {
            #pragma unroll
            for (int j = 0; j < 4; ++j) {
                bf16x8 kb = *(const bf16x8*)(const void*)&Ks[j*16 + l16][kk*32 + quad*8];
                s[j] = __builtin_amdgcn_mfma_f32_16x16x32_bf16(qa[kk], kb, s[j], 0, 0, 0);
            }
        }

        if (jt + 63 > qm + wave * 16) {
            #pragma unroll
            for (int j = 0; j < 4; ++j) {
                int key = jt + j * 16 + l16;
                #pragma unroll
                for (int r = 0; r < 4; ++r) {
                    int row = qm + wave * 16 + quad * 4 + r;
                    if (key > row) s[j][r] = -1e30f;
                }
            }
        }

        f32x4 tmax = s[0];
        #pragma unroll
        for (int j = 1; j < 4; ++j)
            #pragma unroll
            for (int r = 0; r < 4; ++r) tmax[r] = fmaxf(tmax[r], s[j][r]);
        #pragma unroll
        for (int r = 0; r < 4; ++r) {
            float tv = tmax[r];
            #pragma unroll
            for (int d = 1; d < 16; d <<= 1) tv = fmaxf(tv, __shfl_xor(tv, d));
            tmax[r] = tv;
        }
        float scl[4];
        #pragma unroll
        for (int r = 0; r < 4; ++r) {
            float mn = fmaxf(mst[r], tmax[r]);
            scl[r] = __expf(mst[r] - mn);
            mst[r] = mn;
        }
        f32x4 psum = zro;
        #pragma unroll
        for (int j = 0; j < 4; ++j)
            #pragma unroll
            for (int r = 0; r < 4; ++r) {
                float e = __expf(s[j][r] - mst[r]);
                s[j][r] = e;
                psum[r] += e;
            }
        #pragma unroll
        for (int r = 0; r < 4; ++r) {
            float tv = psum[r];
            #pragma unroll
            for (int d = 1; d < 16; d <<= 1) tv += __shfl_xor(tv, d);
            lst[r] = lst[r] * scl[r] + tv;
        }
        #pragma unroll
        for (int j = 0; j < 4; ++j)
            #pragma unroll
            for (int r = 0; r < 4; ++r) oacc[j][r] *= scl[r];

        #pragma unroll
        for (int j = 0; j < 4; ++j)
            #pragma unroll
            for (int r = 0; r < 4; ++r)
                Ps[wave][quad*4 + r][j*16 + l16] = f2b(s[j][r]);
        bf16x8 pa[2];
        pa[0] = *(const bf16x8*)(const void*)&Ps[wave][l16][quad*8];
        pa[1] = *(const bf16x8*)(const void*)&Ps[wave][l16][32 + quad*8];

        #pragma unroll
        for (int kk = 0; kk < 2; ++kk) {
            #pragma unroll
            for (int j = 0; j < 4; ++j) {
                bf16x8 vb = *(const bf16x8*)(const void*)&Vs[j*16 + l16][kk*32 + quad*8];
                oacc[j] = __builtin_amdgcn_mfma_f32_16x16x32_bf16(pa[kk], vb, oacc[j], 0, 0, 0);
            }
        }
        __syncthreads();
    }

    #pragma unroll
    for (int j = 0; j < 4; ++j) {
        #pragma unroll
        for (int r = 0; r < 4; ++r) {
            int t = qm + wave * 16 + quad * 4 + r;
            o[((size_t)(b * 2048 + t)) * 512 + h * 64 + j * 16 + l16] =
                f2b(oacc[j][r] / lst[r]);
        }
    }
}

// ---------------------------------------------------------------------------
static void launch_gemm(int epi, hipStream_t s,
                        const bf16* A, int lda, int zsA,
                        const bf16* Bt, int ldb, int zsB,
                        void* C, int ldc, int zsC,
                        const bf16* bias, const bf16* resid, float scale,
                        int M, int N, int K, int nz)
{
    // few blocks at 128-tile -> use 64-row tiles for occupancy
    bool mt64 = ((M >> 7) * (N >> 7) * nz) < 512;
    dim3 blk(256);
    if (mt64) {
        dim3 g(N / 128, M / 64, nz);
        switch (epi) {
        case 0: gemm_bt<0,64><<<g, blk, 0, s>>>(A, lda, zsA, Bt, ldb, zsB, C, ldc, zsC, bias, resid, scale, K); break;
        case 1: gemm_bt<1,64><<<g, blk, 0, s>>>(A, lda, zsA, Bt, ldb, zsB, C, ldc, zsC, bias, resid, scale, K); break;
        case 2: gemm_bt<2,64><<<g, blk, 0, s>>>(A, lda, zsA, Bt, ldb, zsB, C, ldc, zsC, bias, resid, scale, K); break;
        default: gemm_bt<3,64><<<g, blk, 0, s>>>(A, lda, zsA, Bt, ldb, zsB, C, ldc, zsC, bias, resid, scale, K); break;
        }
    } else {
        dim3 g(N / 128, M / 128, nz);
        switch (epi) {
        case 0: gemm_bt<0,128><<<g, blk, 0, s>>>(A, lda, zsA, Bt, ldb, zsB, C, ldc, zsC, bias, resid, scale, K); break;
        case 1: gemm_bt<1,128><<<g, blk, 0, s>>>(A, lda, zsA, Bt, ldb, zsB, C, ldc, zsC, bias, resid, scale, K); break;
        case 2: gemm_bt<2,128><<<g, blk, 0, s>>>(A, lda, zsA, Bt, ldb, zsB, C, ldc, zsC, bias, resid, scale, K); break;
        default: gemm_bt<3,128><<<g, blk, 0, s>>>(A, lda, zsA, Bt, ldb, zsB, C, ldc, zsC, bias, resid, scale, K); break;
        }
    }
}

extern "C" void kernel_launch(void* const* d_in, const int* in_sizes, int n_in,
                              void* d_out, int out_size, void* d_ws, size_t ws_size,
                              hipStream_t stream)
{
    const void* text  = d_in[0];
    const void* audio = d_in[1];
    const void* video = d_in[2];
    const void* Wa    = d_in[3];
    const void* ba    = d_in[4];
    const void* lna_g = d_in[5];
    const void* lna_b = d_in[6];
    const void* Wvid  = d_in[7];
    const void* bvid  = d_in[8];
    const void* lnv_g = d_in[9];
    const void* lnv_b = d_in[10];
    const void* ln1_g = d_in[11];
    const void* ln1_b = d_in[12];
    const void* Wq    = d_in[13];
    const void* Wkv   = d_in[14];
    const void* qn_g  = d_in[15];
    const void* kn_g  = d_in[16];
    const void* Wo    = d_in[17];
    const void* W1    = d_in[18];
    const void* b1    = d_in[19];
    const void* ln2_g = d_in[20];
    const void* ln2_b = d_in[21];
    const void* W2    = d_in[22];
    const void* b2    = d_in[23];

    char* ws = (char*)d_ws;
    size_t off = 0;
    auto alloc = [&](size_t bytes) -> char* {
        char* p = ws + off;
        off += (bytes + 255) & ~(size_t)255;
        return p;
    };
    const size_t MB = 1024 * 1024;
    int*  flag  = (int*)alloc(256);
    bf16* vecs  = (bf16*)alloc(14 * 4096 * 2);
    bf16* WqkvT = (bf16*)alloc((size_t)1536 * 1024 * 2);
    bf16* WoT   = (bf16*)alloc((size_t)1024 * 512 * 2);
    bf16* W1T   = (bf16*)alloc((size_t)4096 * 1024 * 2);
    bf16* W2T   = (bf16*)alloc((size_t)1024 * 4096 * 2);
    char* regionIn = alloc(24 * MB);
    char* region2  = alloc(32 * MB);
    char* regionH  = alloc(8 * MB);
    char* regionX  = alloc(8 * MB);
    char* regionO  = alloc(4 * MB);
    bf16* qrot    = (bf16*)alloc((size_t)4096 * 1024 * 2);
    bf16* krotPad = (bf16*)alloc((size_t)2 * 2560 * 1024 * 2);
    bf16* VTpad   = (bf16*)alloc((size_t)2 * 1024 * 2560 * 2);
    bf16* attn    = (bf16*)alloc((size_t)8 * 512 * 1024 * 2);

    bf16*  textC  = (bf16*)regionIn;
    bf16*  audioC = textC + (size_t)4096 * 1024;
    bf16*  videoC = textC + (size_t)2 * 4096 * 1024;
    float* qkvF   = (float*)regionIn;
    float* tmpF   = (float*)region2;
    float* xF     = (float*)(region2 + 16 * MB);
    bf16*  g      = (bf16*)region2;
    bf16*  audioT = (bf16*)regionH;
    bf16*  h      = (bf16*)regionH;
    bf16*  videoT = (bf16*)regionX;
    bf16*  x2     = (bf16*)regionX;
    bf16*  WaT    = (bf16*)regionO;
    bf16*  WvT    = WaT + (size_t)1024 * 1024;
    bf16*  o      = (bf16*)regionO;
    bf16*  Qp     = qrot;
    bf16*  Kp     = krotPad;
    bf16*  Vth    = attn;

    bf16* baC   = vecs + 0 * 4096;
    bf16* bvidC = vecs + 1 * 4096;
    bf16* lnagC = vecs + 2 * 4096;
    bf16* lnabC = vecs + 3 * 4096;
    bf16* lnvgC = vecs + 4 * 4096;
    bf16* lnvbC = vecs + 5 * 4096;
    bf16* ln1gC = vecs + 6 * 4096;
    bf16* ln1bC = vecs + 7 * 4096;
    bf16* qngC  = vecs + 8 * 4096;
    bf16* kngC  = vecs + 9 * 4096;
    bf16* b1C   = vecs + 10 * 4096;
    bf16* ln2gC = vecs + 11 * 4096;
    bf16* ln2bC = vecs + 12 * 4096;
    bf16* b2C   = vecs + 13 * 4096;

    // 1) dtype flag
    detect_dtype<<<1, 64, 0, stream>>>((const unsigned short*)text, flag);

    // 2) canonicalize
    const int NTOK = 4096 * 1024;
    convert_bf16<<<2048, 256, 0, stream>>>(text, textC, NTOK, flag);
    convert_bf16<<<2048, 256, 0, stream>>>(audio, audioC, NTOK, flag);
    convert_bf16<<<2048, 256, 0, stream>>>(video, videoC, NTOK, flag);
    VecPack vp;
    const void* vsrc[14] = {ba, bvid, lna_g, lna_b, lnv_g, lnv_b, ln1_g, ln1_b,
                            qn_g, kn_g, b1, ln2_g, ln2_b, b2};
    int vn[14] = {1024, 1024, 1024, 1024, 1024, 1024, 1024, 1024,
                  64, 64, 4096, 4096, 4096, 1024};
    for (int i = 0; i < 14; ++i) { vp.src[i] = vsrc[i]; vp.n[i] = vn[i]; }
    convert_vecs<<<14, 256, 0, stream>>>(vp, vecs, flag);

    // 3) weight transposes
    dim3 tb(32, 8);
    transpose_any<<<dim3(32, 32), tb, 0, stream>>>(Wa, 1024, 1024, (unsigned short*)WaT, 1024, flag);
    transpose_any<<<dim3(32, 32), tb, 0, stream>>>(Wvid, 1024, 1024, (unsigned short*)WvT, 1024, flag);
    transpose_any<<<dim3(16, 32), tb, 0, stream>>>(Wq, 1024, 512, (unsigned short*)WqkvT, 1024, flag);
    transpose_any<<<dim3(32, 32), tb, 0, stream>>>(Wkv, 1024, 1024, (unsigned short*)(WqkvT + (size_t)512 * 1024), 1024, flag);
    transpose_any<<<dim3(32, 16), tb, 0, stream>>>(Wo, 512, 1024, (unsigned short*)WoT, 512, flag);
    transpose_any<<<dim3(128, 32), tb, 0, stream>>>(W1, 1024, 4096, (unsigned short*)W1T, 1024, flag);
    transpose_any<<<dim3(32, 128), tb, 0, stream>>>(W2, 4096, 1024, (unsigned short*)W2T, 4096, flag);

    // 4) adapters
    launch_gemm(0, stream, audioC, 1024, 0, WaT, 1024, 0, tmpF, 1024, 0, baC, nullptr, 1.f, 4096, 1024, 1024, 1);
    ln_rows<float><<<4096, 256, 0, stream>>>(tmpF, 1024, lnagC, lnabC, audioT, 1e-5f);
    launch_gemm(0, stream, videoC, 1024, 0, WvT, 1024, 0, tmpF, 1024, 0, bvidC, nullptr, 1.f, 4096, 1024, 1024, 1);
    ln_rows<float><<<4096, 256, 0, stream>>>(tmpF, 1024, lnvgC, lnvbC, videoT, 1e-5f);

    // 5) pads, rotary, padded-V transpose
    hipMemsetAsync(krotPad, 0, (size_t)2 * 2560 * 1024 * 2, stream);
    hipMemsetAsync(VTpad, 0, (size_t)2 * 1024 * 2560 * 2, stream);
    rotary_kernel<<<4096, 256, 0, stream>>>(textC, audioT, qrot, krotPad);
    for (int b = 0; b < 2; ++b)
        transpose_b16<<<dim3(32, 64), tb, 0, stream>>>(
            (const unsigned short*)(videoT + (size_t)b * 2048 * 1024), 2048, 1024,
            (unsigned short*)(VTpad + (size_t)b * 1024 * 2560), 2560, 512);

    // 6) local attention
    for (int b = 0; b < 2; ++b)
        launch_gemm(0, stream,
                    qrot + (size_t)b * 2048 * 1024, 1024, 512 * 1024,
                    krotPad + (size_t)b * 2560 * 1024, 1024, 512 * 1024,
                    tmpF + (size_t)b * 4 * 512 * 1024, 1024, 512 * 1024,
                    nullptr, nullptr, 1.f, 512, 1024, 1024, 4);
    softmax_local<<<dim3(512, 8), 256, 0, stream>>>(tmpF, attn);
    for (int b = 0; b < 2; ++b)
        launch_gemm(0, stream,
                    attn + (size_t)b * 4 * 512 * 1024, 1024, 512 * 1024,
                    VTpad + (size_t)b * 1024 * 2560, 2560, 512,
                    xF + (size_t)b * 2048 * 1024, 1024, 512 * 1024,
                    nullptr, nullptr, 1.f, 512, 1024, 1024, 4);

    // 7) ln1 -> qkv -> pack -> V transpose -> MFMA flash
    ln_rows<float><<<4096, 256, 0, stream>>>(xF, 1024, ln1gC, ln1bC, h, 1e-5f);
    launch_gemm(0, stream, h, 1024, 0, WqkvT, 1024, 0, qkvF, 1536, 0, nullptr, nullptr, 1.f, 4096, 1536, 1024, 1);
    pack_qk<<<16384, 256, 0, stream>>>(qkvF, Qp, Kp, qngC, kngC);
    transpose_v<<<dim3(2, 64, 16), tb, 0, stream>>>(qkvF, Vth);
    flash_mfma<<<dim3(32, 16), 256, 0, stream>>>(Qp, Kp, Vth, o);

    // 8) x2 = 2*(o@Wo) ; g = gelu(x2@W1+b1) ; ln2 ; out(f32) = g@W2 + b2 + x2
    launch_gemm(1, stream, o, 512, 0, WoT, 512, 0, x2, 1024, 0, nullptr, nullptr, 2.f, 4096, 1024, 512, 1);
    launch_gemm(2, stream, x2, 1024, 0, W1T, 1024, 0, g, 4096, 0, b1C, nullptr, 1.f, 4096, 4096, 1024, 1);
    ln_rows<bf16><<<4096, 256, 0, stream>>>(g, 4096, ln2gC, ln2bC, g, 1e-5f);
    launch_gemm(3, stream, g, 4096, 0, W2T, 4096, 0, d_out, 1024, 0, b2C, x2, 1.f, 4096, 1024, 4096, 1);

    (void)in_sizes; (void)n_in; (void)out_size; (void)ws_size;
}

// Round 7
// 658.063 us; speedup vs baseline: 1.1211x; 1.0039x over previous
//
#include <hip/hip_runtime.h>
#include <hip/hip_bf16.h>

typedef __bf16 bf16;
typedef __bf16 bf16x8 __attribute__((ext_vector_type(8)));
typedef float  f32x4  __attribute__((ext_vector_type(4)));

static __device__ __forceinline__ float b2f(bf16 x) { return (float)x; }
static __device__ __forceinline__ bf16  f2b(float x) { return (bf16)x; }
static __device__ __forceinline__ float ldval(float v) { return v; }
static __device__ __forceinline__ float ldval(bf16 v)  { return (float)v; }

// async global->LDS, 16B per lane; lds dest is wave-uniform base (+lane*16)
static __device__ __forceinline__ void gl_lds16(const bf16* g, bf16* l)
{
    __builtin_amdgcn_global_load_lds(
        (const __attribute__((address_space(1))) void*)g,
        (__attribute__((address_space(3))) void*)l,
        16, 0, 0);
}

// ---------------------------------------------------------------------------
// dtype detection: flag=1 -> f32 inputs.
// ---------------------------------------------------------------------------
__global__ void detect_dtype(const unsigned short* __restrict__ p, int* __restrict__ flag)
{
    if (threadIdx.x == 0 && blockIdx.x == 0) {
        int big = 0;
        for (int i = 0; i < 512; ++i) {
            int e = (p[i] >> 7) & 0xFF;
            if (e >= 0xE0) big++;
        }
        *flag = (big > 0) ? 1 : 0;
    }
}

__global__ __launch_bounds__(256) void convert_bf16(
    const void* __restrict__ src, bf16* __restrict__ dst, int n,
    const int* __restrict__ flag)
{
    int f = *flag;
    for (int i = blockIdx.x * 256 + threadIdx.x; i < n; i += gridDim.x * 256) {
        float v = f ? ((const float*)src)[i] : (float)((const bf16*)src)[i];
        dst[i] = f2b(v);
    }
}

struct VecPack { const void* src[14]; int n[14]; };
__global__ __launch_bounds__(256) void convert_vecs(
    VecPack vp, bf16* __restrict__ dst, const int* __restrict__ flag)
{
    int v = blockIdx.x;
    int f = *flag;
    const void* s = vp.src[v];
    int n = vp.n[v];
    bf16* d = dst + (size_t)v * 4096;
    for (int i = threadIdx.x; i < n; i += 256) {
        float x = f ? ((const float*)s)[i] : (float)((const bf16*)s)[i];
        d[i] = f2b(x);
    }
}

// ---------------------------------------------------------------------------
// GEMM: C[M,N] = A[M,K] @ Bt[n][k]. MT x 128 tile, BK=64, 4 waves.
// global_load_lds w=16 into XOR-swizzled LDS (see R6 notes).
// EPI: 0 = f32 store (+bias)   1 = bf16 store of v*scale
//      2 = bf16 gelu(v+bias)   3 = f32 store (v+bias+resid)
// ---------------------------------------------------------------------------
template <int EPI, int MT>
__global__ __launch_bounds__(256) void gemm_bt(
    const bf16* __restrict__ A0, int lda, int zsA,
    const bf16* __restrict__ B0, int ldb, int zsB,
    void* __restrict__ C0, int ldc, int zsC,
    const bf16* __restrict__ bias, const bf16* __restrict__ resid,
    float scale, int K)
{
    constexpr int IFR = MT / 32;
    __shared__ __align__(16) bf16 As[MT * 64];
    __shared__ __align__(16) bf16 Bs[128 * 64];
    const int z = blockIdx.z;
    const bf16* A  = A0 + (size_t)z * zsA;
    const bf16* Bt = B0 + (size_t)z * zsB;
    const int tid  = threadIdx.x;
    const int lane = tid & 63, wave = tid >> 6;
    const int quad = lane >> 4, l16 = lane & 15;
    const size_t tm = (size_t)blockIdx.y * MT, tn = (size_t)blockIdx.x * 128;
    const int wm = (wave >> 1) * (MT / 2), wn = (wave & 1) * 64;
    const int srow = lane >> 3;
    const int scol = ((lane & 7) ^ srow) * 8;

    f32x4 acc[IFR][4];
    const f32x4 zro = {0.f, 0.f, 0.f, 0.f};
    #pragma unroll
    for (int i = 0; i < IFR; ++i)
        #pragma unroll
        for (int j = 0; j < 4; ++j) acc[i][j] = zro;

    const int swzA = l16 & 7;
    for (int k0 = 0; k0 < K; k0 += 64) {
        #pragma unroll
        for (int i = 0; i < IFR; ++i) {
            int chunk = (wave * IFR + i) * 64;
            int row = (chunk >> 3) + srow;
            gl_lds16(A + (tm + row) * (size_t)lda + k0 + scol, As + (size_t)chunk * 8);
        }
        #pragma unroll
        for (int i = 0; i < 4; ++i) {
            int chunk = (wave * 4 + i) * 64;
            int row = (chunk >> 3) + srow;
            gl_lds16(Bt + (tn + row) * (size_t)ldb + k0 + scol, Bs + (size_t)chunk * 8);
        }
        __syncthreads();
        #pragma unroll
        for (int kk = 0; kk < 2; ++kk) {
            bf16x8 af[IFR], bfr[4];
            #pragma unroll
            for (int i = 0; i < IFR; ++i) {
                int row = wm + i * 16 + l16;
                af[i] = *(const bf16x8*)(const void*)&As[(row * 8 + ((kk*4 + quad) ^ swzA)) * 8];
            }
            #pragma unroll
            for (int j = 0; j < 4; ++j) {
                int row = wn + j * 16 + l16;
                bfr[j] = *(const bf16x8*)(const void*)&Bs[(row * 8 + ((kk*4 + quad) ^ swzA)) * 8];
            }
            #pragma unroll
            for (int i = 0; i < IFR; ++i)
                #pragma unroll
                for (int j = 0; j < 4; ++j)
                    acc[i][j] = __builtin_amdgcn_mfma_f32_16x16x32_bf16(
                        af[i], bfr[j], acc[i][j], 0, 0, 0);
        }
        __syncthreads();
    }

    float* Cf = (float*)C0;
    bf16*  Cb = (bf16*)C0;
    #pragma unroll
    for (int i = 0; i < IFR; ++i) {
        #pragma unroll
        for (int j = 0; j < 4; ++j) {
            size_t col = tn + wn + j*16 + l16;
            float bb = bias ? b2f(bias[col]) : 0.f;
            #pragma unroll
            for (int r = 0; r < 4; ++r) {
                size_t row = tm + wm + i*16 + quad*4 + r;
                float v = acc[i][j][r] + bb;
                size_t off = (size_t)z * zsC + row * (size_t)ldc + col;
                if (EPI == 0) {
                    Cf[off] = v;
                } else if (EPI == 1) {
                    Cb[off] = f2b(v * scale);
                } else if (EPI == 2) {
                    float g = 0.5f * v * (1.f + tanhf(0.7978845608028654f *
                                  (v + 0.044715f * v * v * v)));
                    Cb[off] = f2b(g);
                } else {
                    Cf[off] = v + b2f(resid[row * (size_t)ldc + col]);
                }
            }
        }
    }
}

// ---------------------------------------------------------------------------
// bf16 transpose: out[c*ldo + off + r] = in[r*C + c]
// ---------------------------------------------------------------------------
__global__ void transpose_b16(const unsigned short* __restrict__ in, int R, int C,
                              unsigned short* __restrict__ out, int ldo, int off)
{
    __shared__ unsigned short t[32][33];
    int c0 = blockIdx.x * 32, r0 = blockIdx.y * 32;
    int tx = threadIdx.x, ty = threadIdx.y;
    for (int i = ty; i < 32; i += 8)
        t[i][tx] = in[(size_t)(r0 + i) * C + c0 + tx];
    __syncthreads();
    for (int i = ty; i < 32; i += 8)
        out[(size_t)(c0 + i) * ldo + off + r0 + tx] = t[tx][i];
}

__global__ void transpose_any(const void* __restrict__ in, int R, int C,
                              unsigned short* __restrict__ out, int ldo,
                              const int* __restrict__ flag)
{
    __shared__ unsigned short t[32][33];
    int f = *flag;
    int c0 = blockIdx.x * 32, r0 = blockIdx.y * 32;
    int tx = threadIdx.x, ty = threadIdx.y;
    for (int i = ty; i < 32; i += 8) {
        size_t idx = (size_t)(r0 + i) * C + c0 + tx;
        bf16 v = f ? f2b(((const float*)in)[idx]) : ((const bf16*)in)[idx];
        t[i][tx] = *(unsigned short*)&v;
    }
    __syncthreads();
    for (int i = ty; i < 32; i += 8)
        out[(size_t)(c0 + i) * ldo + r0 + tx] = t[tx][i];
}

// ---------------------------------------------------------------------------
// V transpose into per-head Vt[bh][64][2048] bf16.
// ---------------------------------------------------------------------------
__global__ void transpose_v(const float* __restrict__ qkv, bf16* __restrict__ Vt)
{
    __shared__ float t[32][33];
    int bh = blockIdx.z, b = bh >> 3, h = bh & 7;
    const float* src = qkv + (size_t)b * 2048 * 1536 + 1024 + h * 64;
    int c0 = blockIdx.x * 32, r0 = blockIdx.y * 32;
    int tx = threadIdx.x, ty = threadIdx.y;
    for (int i = ty; i < 32; i += 8)
        t[i][tx] = src[(size_t)(r0 + i) * 1536 + c0 + tx];
    __syncthreads();
    bf16* dst = Vt + (size_t)bh * 64 * 2048;
    for (int i = ty; i < 32; i += 8)
        dst[(size_t)(c0 + i) * 2048 + r0 + tx] = f2b(t[tx][i]);
}

// ---------------------------------------------------------------------------
// Row LayerNorm: one block per row.
// ---------------------------------------------------------------------------
template <typename Tin>
__global__ __launch_bounds__(256) void ln_rows(
    const Tin* __restrict__ in, int C,
    const bf16* __restrict__ g, const bf16* __restrict__ b,
    bf16* __restrict__ out, float eps)
{
    const int row = blockIdx.x, tid = threadIdx.x;
    const Tin* p = in + (size_t)row * C;
    float s = 0.f, ss = 0.f;
    for (int c = tid; c < C; c += 256) {
        float v = ldval(p[c]);
        s += v; ss += v * v;
    }
    #pragma unroll
    for (int d = 32; d > 0; d >>= 1) { s += __shfl_xor(s, d); ss += __shfl_xor(ss, d); }
    __shared__ float red[2][4];
    int wave = tid >> 6, lane = tid & 63;
    if (lane == 0) { red[0][wave] = s; red[1][wave] = ss; }
    __syncthreads();
    s  = red[0][0] + red[0][1] + red[0][2] + red[0][3];
    ss = red[1][0] + red[1][1] + red[1][2] + red[1][3];
    float mu   = s / C;
    float var  = ss / C - mu * mu;
    float rstd = rsqrtf(var + eps);
    bf16* q = out + (size_t)row * C;
    for (int c = tid; c < C; c += 256) {
        float v = ldval(p[c]);
        q[c] = f2b((v - mu) * rstd * b2f(g[c]) + b2f(b[c]));
    }
}

// ---------------------------------------------------------------------------
// Rotary: qrot = rope(text)*DIM^-0.5 ; krotPad[b][512+t] = rope(audio_t).
// ---------------------------------------------------------------------------
__global__ __launch_bounds__(256) void rotary_kernel(
    const bf16* __restrict__ text, const bf16* __restrict__ audioT,
    bf16* __restrict__ qrot, bf16* __restrict__ krotPad)
{
    int row = blockIdx.x;
    int t = row & 2047, b = row >> 11;
    int tid = threadIdx.x;
    const float lg = 9.210340371976184f / 512.f;
    size_t base = (size_t)row * 1024;
    size_t kb = ((size_t)(b * 2560 + 512 + t)) * 1024;
    for (int c = tid; c < 512; c += 256) {
        float invf = __expf(-(float)c * lg);
        float th = (float)t * invf;
        float sn, cs;
        sincosf(th, &sn, &cs);
        float q1 = b2f(text[base + c]), q2 = b2f(text[base + c + 512]);
        qrot[base + c]       = f2b((q1 * cs - q2 * sn) * 0.03125f);
        qrot[base + c + 512] = f2b((q2 * cs + q1 * sn) * 0.03125f);
        float k1 = b2f(audioT[base + c]), k2 = b2f(audioT[base + c + 512]);
        krotPad[kb + c]       = f2b(k1 * cs - k2 * sn);
        krotPad[kb + c + 512] = f2b(k2 * cs + k1 * sn);
    }
}

// ---------------------------------------------------------------------------
// Local-attention masked softmax. sim [b][w][512][1024] f32 -> attn bf16.
// ---------------------------------------------------------------------------
__global__ __launch_bounds__(256) void softmax_local(
    const float* __restrict__ sim, bf16* __restrict__ attn)
{
    int i  = blockIdx.x;
    int zz = blockIdx.y;
    int w  = zz & 3;
    int tid = threadIdx.x;
    const float* p = sim + ((size_t)zz * 512 + i) * 1024;
    bf16* q = attn + ((size_t)zz * 512 + i) * 1024;
    int jlo = (w == 0) ? 512 : 0;
    int jhi = 512 + i;
    float m = -1e30f;
    #pragma unroll
    for (int k = 0; k < 4; ++k) {
        int c = tid + k * 256;
        if (c >= jlo && c <= jhi) m = fmaxf(m, p[c]);
    }
    #pragma unroll
    for (int d = 32; d > 0; d >>= 1) m = fmaxf(m, __shfl_xor(m, d));
    __shared__ float red[2][4];
    int wave = tid >> 6, lane = tid & 63;
    if (lane == 0) red[0][wave] = m;
    __syncthreads();
    m = fmaxf(fmaxf(red[0][0], red[0][1]), fmaxf(red[0][2], red[0][3]));
    float pv[4];
    float s = 0.f;
    #pragma unroll
    for (int k = 0; k < 4; ++k) {
        int c = tid + k * 256;
        float e = (c >= jlo && c <= jhi) ? __expf(p[c] - m) : 0.f;
        pv[k] = e; s += e;
    }
    #pragma unroll
    for (int d = 32; d > 0; d >>= 1) s += __shfl_xor(s, d);
    if (lane == 0) red[1][wave] = s;
    __syncthreads();
    s = red[1][0] + red[1][1] + red[1][2] + red[1][3];
    float inv = 1.f / s;
    #pragma unroll
    for (int k = 0; k < 4; ++k) q[tid + k * 256] = f2b(pv[k] * inv);
}

// ---------------------------------------------------------------------------
// pack_qk: RMSNorm q/k from qkv f32 [4096][1536] -> per-head bf16 buffers.
// ---------------------------------------------------------------------------
__global__ __launch_bounds__(256) void pack_qk(
    const float* __restrict__ qkv, bf16* __restrict__ Qp, bf16* __restrict__ Kp,
    const bf16* __restrict__ qn_g, const bf16* __restrict__ kn_g)
{
    int gid  = blockIdx.x * 4 + (threadIdx.x >> 6);
    int lane = threadIdx.x & 63;
    int token = gid >> 4, r = gid & 15, part = r >> 3, h = r & 7;
    const float* p = qkv + (size_t)token * 1536 + part * 512 + h * 64 + lane;
    float v = *p;
    float ss = v * v;
    #pragma unroll
    for (int d = 32; d > 0; d >>= 1) ss += __shfl_xor(ss, d);
    float sc = rsqrtf(ss * (1.f / 64.f) + 1e-6f);
    const bf16* gw = part ? kn_g : qn_g;
    float outv = v * sc * b2f(gw[lane]);
    if (!part) outv *= 0.125f;
    int b = token >> 11, t = token & 2047;
    bf16* dst = (part ? Kp : Qp) + ((size_t)(b * 8 + h) * 2048 + t) * 64 + lane;
    *dst = f2b(outv);
}

// ---------------------------------------------------------------------------
// Key-split MFMA flash attention (causal, D=64).
// Grid (32 qb, 4 chunks, 16 bh). Chunk = up to 8 key-tiles (512 keys).
// nch(qb) = qb/8+1. Single-chunk rows (qb<8) write o directly; otherwise
// unnormalized f32 O + per-row (m,l) partials merged by flash_combine.
// ---------------------------------------------------------------------------
__global__ __launch_bounds__(256) void flash_split(
    const bf16* __restrict__ Qp, const bf16* __restrict__ Kp,
    const bf16* __restrict__ Vt, bf16* __restrict__ o,
    float* __restrict__ Opart, float* __restrict__ MLpart)
{
    const int qb = blockIdx.x;
    const int chunk = blockIdx.y;
    const int nch = (qb >> 3) + 1;
    if (chunk >= nch) return;
    __shared__ __align__(16) bf16 Ks[64][72];
    __shared__ __align__(16) bf16 Vs[64][72];
    __shared__ __align__(16) bf16 Ps[4][16][72];
    const int bh = blockIdx.z, b = bh >> 3, h = bh & 7;
    const int qm = qb * 64;
    const int jt0 = chunk * 512;
    const int jt1 = min(jt0 + 512, qm + 64);
    const int tid = threadIdx.x, wave = tid >> 6, lane = tid & 63;
    const int quad = lane >> 4, l16 = lane & 15;
    const bf16* Qg = Qp + (size_t)bh * 2048 * 64;
    const bf16* Kg = Kp + (size_t)bh * 2048 * 64;
    const bf16* Vg = Vt + (size_t)bh * 64 * 2048;

    const int qrow = qm + wave * 16 + l16;
    bf16x8 qa[2];
    qa[0] = *(const bf16x8*)(const void*)(Qg + (size_t)qrow * 64 + quad * 8);
    qa[1] = *(const bf16x8*)(const void*)(Qg + (size_t)qrow * 64 + 32 + quad * 8);

    f32x4 oacc[4];
    const f32x4 zro = {0.f, 0.f, 0.f, 0.f};
    #pragma unroll
    for (int j = 0; j < 4; ++j) oacc[j] = zro;
    float mst[4] = {-1e30f, -1e30f, -1e30f, -1e30f};
    float lst[4] = {0.f, 0.f, 0.f, 0.f};

    const int ldr = tid >> 2, ldc = (tid & 3) * 16;
    for (int jt = jt0; jt < jt1; jt += 64) {
        *(uint4*)(void*)&Ks[ldr][ldc] =
            *(const uint4*)(const void*)(Kg + (size_t)(jt + ldr) * 64 + ldc);
        *(uint4*)(void*)&Ks[ldr][ldc + 8] =
            *(const uint4*)(const void*)(Kg + (size_t)(jt + ldr) * 64 + ldc + 8);
        *(uint4*)(void*)&Vs[ldr][ldc] =
            *(const uint4*)(const void*)(Vg + (size_t)ldr * 2048 + jt + ldc);
        *(uint4*)(void*)&Vs[ldr][ldc + 8] =
            *(const uint4*)(const void*)(Vg + (size_t)ldr * 2048 + jt + ldc + 8);
        __syncthreads();

        f32x4 s[4];
        #pragma unroll
        for (int j = 0; j < 4; ++j) s[j] = zro;
        #pragma unroll
        for (int kk = 0; kk < 2; ++kk) {
            #pragma unroll
            for (int j = 0; j < 4; ++j) {
                bf16x8 kb = *(const bf16x8*)(const void*)&Ks[j*16 + l16][kk*32 + quad*8];
                s[j] = __builtin_amdgcn_mfma_f32_16x16x32_bf16(qa[kk], kb, s[j], 0, 0, 0);
            }
        }

        if (jt + 63 > qm + wave * 16) {       // only diagonal tile clips
            #pragma unroll
            for (int j = 0; j < 4; ++j) {
                int key = jt + j * 16 + l16;
                #pragma unroll
                for (int r = 0; r < 4; ++r) {
                    int row = qm + wave * 16 + quad * 4 + r;
                    if (key > row) s[j][r] = -1e30f;
                }
            }
        }

        f32x4 tmax = s[0];
        #pragma unroll
        for (int j = 1; j < 4; ++j)
            #pragma unroll
            for (int r = 0; r < 4; ++r) tmax[r] = fmaxf(tmax[r], s[j][r]);
        #pragma unroll
        for (int r = 0; r < 4; ++r) {
            float tv = tmax[r];
            #pragma unroll
            for (int d = 1; d < 16; d <<= 1) tv = fmaxf(tv, __shfl_xor(tv, d));
            tmax[r] = tv;
        }
        float scl[4];
        #pragma unroll
        for (int r = 0; r < 4; ++r) {
            float mn = fmaxf(mst[r], tmax[r]);
            scl[r] = __expf(mst[r] - mn);
            mst[r] = mn;
        }
        f32x4 psum = zro;
        #pragma unroll
        for (int j = 0; j < 4; ++j)
            #pragma unroll
            for (int r = 0; r < 4; ++r) {
                float e = __expf(s[j][r] - mst[r]);
                s[j][r] = e;
                psum[r] += e;
            }
        #pragma unroll
        for (int r = 0; r < 4; ++r) {
            float tv = psum[r];
            #pragma unroll
            for (int d = 1; d < 16; d <<= 1) tv += __shfl_xor(tv, d);
            lst[r] = lst[r] * scl[r] + tv;
        }
        #pragma unroll
        for (int j = 0; j < 4; ++j)
            #pragma unroll
            for (int r = 0; r < 4; ++r) oacc[j][r] *= scl[r];

        #pragma unroll
        for (int j = 0; j < 4; ++j)
            #pragma unroll
            for (int r = 0; r < 4; ++r)
                Ps[wave][quad*4 + r][j*16 + l16] = f2b(s[j][r]);
        bf16x8 pa[2];
        pa[0] = *(const bf16x8*)(const void*)&Ps[wave][l16][quad*8];
        pa[1] = *(const bf16x8*)(const void*)&Ps[wave][l16][32 + quad*8];

        #pragma unroll
        for (int kk = 0; kk < 2; ++kk) {
            #pragma unroll
            for (int j = 0; j < 4; ++j) {
                bf16x8 vb = *(const bf16x8*)(const void*)&Vs[j*16 + l16][kk*32 + quad*8];
                oacc[j] = __builtin_amdgcn_mfma_f32_16x16x32_bf16(pa[kk], vb, oacc[j], 0, 0, 0);
            }
        }
        __syncthreads();
    }

    if (nch == 1) {
        #pragma unroll
        for (int j = 0; j < 4; ++j) {
            #pragma unroll
            for (int r = 0; r < 4; ++r) {
                int t = qm + wave * 16 + quad * 4 + r;
                o[((size_t)(b * 2048 + t)) * 512 + h * 64 + j * 16 + l16] =
                    f2b(oacc[j][r] / lst[r]);
            }
        }
    } else {
        int pidx = (bh * 32 + qb) * 4 + chunk;
        float* Od = Opart + (size_t)pidx * 4096;
        #pragma unroll
        for (int j = 0; j < 4; ++j)
            #pragma unroll
            for (int r = 0; r < 4; ++r) {
                int row = wave * 16 + quad * 4 + r;
                Od[row * 64 + j * 16 + l16] = oacc[j][r];
            }
        if (l16 == 0) {
            #pragma unroll
            for (int r = 0; r < 4; ++r) {
                int row = wave * 16 + quad * 4 + r;
                MLpart[(size_t)pidx * 128 + row]      = mst[r];
                MLpart[(size_t)pidx * 128 + 64 + row] = lst[r];
            }
        }
    }
}

// ---------------------------------------------------------------------------
// Merge key-split partials for qb >= 8. Grid (24, 16), 256 thr.
// ---------------------------------------------------------------------------
__global__ __launch_bounds__(256) void flash_combine(
    const float* __restrict__ Opart, const float* __restrict__ MLpart,
    bf16* __restrict__ o)
{
    int qb = blockIdx.x + 8;
    int bh = blockIdx.y, b = bh >> 3, h = bh & 7;
    int nch = (qb >> 3) + 1;
    int row = threadIdx.x >> 2;
    int d0 = (threadIdx.x & 3) * 16;
    int base = (bh * 32 + qb) * 4;
    float m[4], l[4], w[4];
    float mstar = -1e30f;
    for (int c = 0; c < nch; ++c) {
        m[c] = MLpart[(size_t)(base + c) * 128 + row];
        l[c] = MLpart[(size_t)(base + c) * 128 + 64 + row];
        mstar = fmaxf(mstar, m[c]);
    }
    float lstar = 0.f;
    for (int c = 0; c < nch; ++c) {
        w[c] = __expf(m[c] - mstar);
        lstar += l[c] * w[c];
    }
    float inv = 1.f / lstar;
    int t = qb * 64 + row;
    bf16* op = o + ((size_t)(b * 2048 + t)) * 512 + h * 64 + d0;
    #pragma unroll 4
    for (int dd = 0; dd < 16; ++dd) {
        float acc = 0.f;
        for (int c = 0; c < nch; ++c)
            acc += Opart[(size_t)(base + c) * 4096 + row * 64 + d0 + dd] * w[c];
        op[dd] = f2b(acc * inv);
    }
}

// ---------------------------------------------------------------------------
static void launch_gemm(int epi, hipStream_t s,
                        const bf16* A, int lda, int zsA,
                        const bf16* Bt, int ldb, int zsB,
                        void* C, int ldc, int zsC,
                        const bf16* bias, const bf16* resid, float scale,
                        int M, int N, int K, int nz)
{
    bool mt64 = ((M >> 7) * (N >> 7) * nz) < 512;
    dim3 blk(256);
    if (mt64) {
        dim3 g(N / 128, M / 64, nz);
        switch (epi) {
        case 0: gemm_bt<0,64><<<g, blk, 0, s>>>(A, lda, zsA, Bt, ldb, zsB, C, ldc, zsC, bias, resid, scale, K); break;
        case 1: gemm_bt<1,64><<<g, blk, 0, s>>>(A, lda, zsA, Bt, ldb, zsB, C, ldc, zsC, bias, resid, scale, K); break;
        case 2: gemm_bt<2,64><<<g, blk, 0, s>>>(A, lda, zsA, Bt, ldb, zsB, C, ldc, zsC, bias, resid, scale, K); break;
        default: gemm_bt<3,64><<<g, blk, 0, s>>>(A, lda, zsA, Bt, ldb, zsB, C, ldc, zsC, bias, resid, scale, K); break;
        }
    } else {
        dim3 g(N / 128, M / 128, nz);
        switch (epi) {
        case 0: gemm_bt<0,128><<<g, blk, 0, s>>>(A, lda, zsA, Bt, ldb, zsB, C, ldc, zsC, bias, resid, scale, K); break;
        case 1: gemm_bt<1,128><<<g, blk, 0, s>>>(A, lda, zsA, Bt, ldb, zsB, C, ldc, zsC, bias, resid, scale, K); break;
        case 2: gemm_bt<2,128><<<g, blk, 0, s>>>(A, lda, zsA, Bt, ldb, zsB, C, ldc, zsC, bias, resid, scale, K); break;
        default: gemm_bt<3,128><<<g, blk, 0, s>>>(A, lda, zsA, Bt, ldb, zsB, C, ldc, zsC, bias, resid, scale, K); break;
        }
    }
}

extern "C" void kernel_launch(void* const* d_in, const int* in_sizes, int n_in,
                              void* d_out, int out_size, void* d_ws, size_t ws_size,
                              hipStream_t stream)
{
    const void* text  = d_in[0];
    const void* audio = d_in[1];
    const void* video = d_in[2];
    const void* Wa    = d_in[3];
    const void* ba    = d_in[4];
    const void* lna_g = d_in[5];
    const void* lna_b = d_in[6];
    const void* Wvid  = d_in[7];
    const void* bvid  = d_in[8];
    const void* lnv_g = d_in[9];
    const void* lnv_b = d_in[10];
    const void* ln1_g = d_in[11];
    const void* ln1_b = d_in[12];
    const void* Wq    = d_in[13];
    const void* Wkv   = d_in[14];
    const void* qn_g  = d_in[15];
    const void* kn_g  = d_in[16];
    const void* Wo    = d_in[17];
    const void* W1    = d_in[18];
    const void* b1    = d_in[19];
    const void* ln2_g = d_in[20];
    const void* ln2_b = d_in[21];
    const void* W2    = d_in[22];
    const void* b2    = d_in[23];

    char* ws = (char*)d_ws;
    size_t off = 0;
    auto alloc = [&](size_t bytes) -> char* {
        char* p = ws + off;
        off += (bytes + 255) & ~(size_t)255;
        return p;
    };
    const size_t MB = 1024 * 1024;
    int*  flag  = (int*)alloc(256);
    bf16* vecs  = (bf16*)alloc(14 * 4096 * 2);
    bf16* WqkvT = (bf16*)alloc((size_t)1536 * 1024 * 2);
    bf16* WoT   = (bf16*)alloc((size_t)1024 * 512 * 2);
    bf16* W1T   = (bf16*)alloc((size_t)4096 * 1024 * 2);
    bf16* W2T   = (bf16*)alloc((size_t)1024 * 4096 * 2);
    char* regionIn = alloc(24 * MB);
    char* region2  = alloc(32 * MB);
    char* regionH  = alloc(8 * MB);
    char* regionX  = alloc(8 * MB);
    char* regionO  = alloc(4 * MB);
    bf16* qrot    = (bf16*)alloc((size_t)4096 * 1024 * 2);
    bf16* krotPad = (bf16*)alloc((size_t)2 * 2560 * 1024 * 2);
    bf16* VTpad   = (bf16*)alloc((size_t)2 * 1024 * 2560 * 2);
    bf16* attn    = (bf16*)alloc((size_t)8 * 512 * 1024 * 2);

    bf16*  textC  = (bf16*)regionIn;
    bf16*  audioC = textC + (size_t)4096 * 1024;
    bf16*  videoC = textC + (size_t)2 * 4096 * 1024;
    float* qkvF   = (float*)regionIn;
    float* tmpF   = (float*)region2;
    float* xF     = (float*)(region2 + 16 * MB);
    bf16*  g      = (bf16*)region2;
    bf16*  audioT = (bf16*)regionH;
    bf16*  h      = (bf16*)regionH;
    bf16*  videoT = (bf16*)regionX;
    bf16*  x2     = (bf16*)regionX;
    bf16*  WaT    = (bf16*)regionO;
    bf16*  WvT    = WaT + (size_t)1024 * 1024;
    bf16*  o      = (bf16*)regionO;
    bf16*  Qp     = qrot;
    bf16*  Kp     = krotPad;
    bf16*  Vth    = attn;
    // flash partials: regionIn(24MB)+region2(32MB) are contiguous and dead
    // between flash_split and flash_combine (qkvF/tmpF/xF consumed; g written
    // only after combine completes). Opart 33.5 MB + ML 1 MB span them.
    float* Opart  = (float*)regionIn;                       // [16*32*4][4096] f32
    float* MLpart = Opart + (size_t)16 * 32 * 4 * 4096;     // [16*32*4][128] f32

    bf16* baC   = vecs + 0 * 4096;
    bf16* bvidC = vecs + 1 * 4096;
    bf16* lnagC = vecs + 2 * 4096;
    bf16* lnabC = vecs + 3 * 4096;
    bf16* lnvgC = vecs + 4 * 4096;
    bf16* lnvbC = vecs + 5 * 4096;
    bf16* ln1gC = vecs + 6 * 4096;
    bf16* ln1bC = vecs + 7 * 4096;
    bf16* qngC  = vecs + 8 * 4096;
    bf16* kngC  = vecs + 9 * 4096;
    bf16* b1C   = vecs + 10 * 4096;
    bf16* ln2gC = vecs + 11 * 4096;
    bf16* ln2bC = vecs + 12 * 4096;
    bf16* b2C   = vecs + 13 * 4096;

    // 1) dtype flag
    detect_dtype<<<1, 64, 0, stream>>>((const unsigned short*)text, flag);

    // 2) canonicalize
    const int NTOK = 4096 * 1024;
    convert_bf16<<<2048, 256, 0, stream>>>(text, textC, NTOK, flag);
    convert_bf16<<<2048, 256, 0, stream>>>(audio, audioC, NTOK, flag);
    convert_bf16<<<2048, 256, 0, stream>>>(video, videoC, NTOK, flag);
    VecPack vp;
    const void* vsrc[14] = {ba, bvid, lna_g, lna_b, lnv_g, lnv_b, ln1_g, ln1_b,
                            qn_g, kn_g, b1, ln2_g, ln2_b, b2};
    int vn[14] = {1024, 1024, 1024, 1024, 1024, 1024, 1024, 1024,
                  64, 64, 4096, 4096, 4096, 1024};
    for (int i = 0; i < 14; ++i) { vp.src[i] = vsrc[i]; vp.n[i] = vn[i]; }
    convert_vecs<<<14, 256, 0, stream>>>(vp, vecs, flag);

    // 3) weight transposes
    dim3 tb(32, 8);
    transpose_any<<<dim3(32, 32), tb, 0, stream>>>(Wa, 1024, 1024, (unsigned short*)WaT, 1024, flag);
    transpose_any<<<dim3(32, 32), tb, 0, stream>>>(Wvid, 1024, 1024, (unsigned short*)WvT, 1024, flag);
    transpose_any<<<dim3(16, 32), tb, 0, stream>>>(Wq, 1024, 512, (unsigned short*)WqkvT, 1024, flag);
    transpose_any<<<dim3(32, 32), tb, 0, stream>>>(Wkv, 1024, 1024, (unsigned short*)(WqkvT + (size_t)512 * 1024), 1024, flag);
    transpose_any<<<dim3(32, 16), tb, 0, stream>>>(Wo, 512, 1024, (unsigned short*)WoT, 512, flag);
    transpose_any<<<dim3(128, 32), tb, 0, stream>>>(W1, 1024, 4096, (unsigned short*)W1T, 1024, flag);
    transpose_any<<<dim3(32, 128), tb, 0, stream>>>(W2, 4096, 1024, (unsigned short*)W2T, 4096, flag);

    // 4) adapters
    launch_gemm(0, stream, audioC, 1024, 0, WaT, 1024, 0, tmpF, 1024, 0, baC, nullptr, 1.f, 4096, 1024, 1024, 1);
    ln_rows<float><<<4096, 256, 0, stream>>>(tmpF, 1024, lnagC, lnabC, audioT, 1e-5f);
    launch_gemm(0, stream, videoC, 1024, 0, WvT, 1024, 0, tmpF, 1024, 0, bvidC, nullptr, 1.f, 4096, 1024, 1024, 1);
    ln_rows<float><<<4096, 256, 0, stream>>>(tmpF, 1024, lnvgC, lnvbC, videoT, 1e-5f);

    // 5) pads, rotary, padded-V transpose
    hipMemsetAsync(krotPad, 0, (size_t)2 * 2560 * 1024 * 2, stream);
    hipMemsetAsync(VTpad, 0, (size_t)2 * 1024 * 2560 * 2, stream);
    rotary_kernel<<<4096, 256, 0, stream>>>(textC, audioT, qrot, krotPad);
    for (int b = 0; b < 2; ++b)
        transpose_b16<<<dim3(32, 64), tb, 0, stream>>>(
            (const unsigned short*)(videoT + (size_t)b * 2048 * 1024), 2048, 1024,
            (unsigned short*)(VTpad + (size_t)b * 1024 * 2560), 2560, 512);

    // 6) local attention
    for (int b = 0; b < 2; ++b)
        launch_gemm(0, stream,
                    qrot + (size_t)b * 2048 * 1024, 1024, 512 * 1024,
                    krotPad + (size_t)b * 2560 * 1024, 1024, 512 * 1024,
                    tmpF + (size_t)b * 4 * 512 * 1024, 1024, 512 * 1024,
                    nullptr, nullptr, 1.f, 512, 1024, 1024, 4);
    softmax_local<<<dim3(512, 8), 256, 0, stream>>>(tmpF, attn);
    for (int b = 0; b < 2; ++b)
        launch_gemm(0, stream,
                    attn + (size_t)b * 4 * 512 * 1024, 1024, 512 * 1024,
                    VTpad + (size_t)b * 1024 * 2560, 2560, 512,
                    xF + (size_t)b * 2048 * 1024, 1024, 512 * 1024,
                    nullptr, nullptr, 1.f, 512, 1024, 1024, 4);

    // 7) ln1 -> qkv -> pack -> V transpose -> key-split flash -> combine
    ln_rows<float><<<4096, 256, 0, stream>>>(xF, 1024, ln1gC, ln1bC, h, 1e-5f);
    launch_gemm(0, stream, h, 1024, 0, WqkvT, 1024, 0, qkvF, 1536, 0, nullptr, nullptr, 1.f, 4096, 1536, 1024, 1);
    pack_qk<<<16384, 256, 0, stream>>>(qkvF, Qp, Kp, qngC, kngC);
    transpose_v<<<dim3(2, 64, 16), tb, 0, stream>>>(qkvF, Vth);
    flash_split<<<dim3(32, 4, 16), 256, 0, stream>>>(Qp, Kp, Vth, o, Opart, MLpart);
    flash_combine<<<dim3(24, 16), 256, 0, stream>>>(Opart, MLpart, o);

    // 8) x2 = 2*(o@Wo) ; g = gelu(x2@W1+b1) ; ln2 ; out(f32) = g@W2 + b2 + x2
    launch_gemm(1, stream, o, 512, 0, WoT, 512, 0, x2, 1024, 0, nullptr, nullptr, 2.f, 4096, 1024, 512, 1);
    launch_gemm(2, stream, x2, 1024, 0, W1T, 1024, 0, g, 4096, 0, b1C, nullptr, 1.f, 4096, 4096, 1024, 1);
    ln_rows<bf16><<<4096, 256, 0, stream>>>(g, 4096, ln2gC, ln2bC, g, 1e-5f);
    launch_gemm(3, stream, g, 4096, 0, W2T, 4096, 0, d_out, 1024, 0, b2C, x2, 1.f, 4096, 1024, 4096, 1);

    (void)in_sizes; (void)n_in; (void)out_size; (void)ws_size;
}

// Round 8
// 602.191 us; speedup vs baseline: 1.2251x; 1.0928x over previous
//
#include <hip/hip_runtime.h>
#include <hip/hip_bf16.h>

typedef __bf16 bf16;
typedef __bf16 bf16x8 __attribute__((ext_vector_type(8)));
typedef float  f32x4  __attribute__((ext_vector_type(4)));

static __device__ __forceinline__ float b2f(bf16 x) { return (float)x; }
static __device__ __forceinline__ bf16  f2b(float x) { return (bf16)x; }
static __device__ __forceinline__ float ldval(float v) { return v; }
static __device__ __forceinline__ float ldval(bf16 v)  { return (float)v; }

// async global->LDS, 16B per lane; lds dest is wave-uniform base (+lane*16)
static __device__ __forceinline__ void gl_lds16(const bf16* g, bf16* l)
{
    __builtin_amdgcn_global_load_lds(
        (const __attribute__((address_space(1))) void*)g,
        (__attribute__((address_space(3))) void*)l,
        16, 0, 0);
}

// ---------------------------------------------------------------------------
// dtype detection: flag=1 -> f32 inputs.
// ---------------------------------------------------------------------------
__global__ void detect_dtype(const unsigned short* __restrict__ p, int* __restrict__ flag)
{
    if (threadIdx.x == 0 && blockIdx.x == 0) {
        int big = 0;
        for (int i = 0; i < 512; ++i) {
            int e = (p[i] >> 7) & 0xFF;
            if (e >= 0xE0) big++;
        }
        *flag = (big > 0) ? 1 : 0;
    }
}

// convert two tensors in one launch (grid split in half)
__global__ __launch_bounds__(256) void convert2(
    const void* __restrict__ sa, const void* __restrict__ sb,
    bf16* __restrict__ da, bf16* __restrict__ db, int n,
    const int* __restrict__ flag)
{
    int f = *flag;
    int half = gridDim.x >> 1;
    const void* s = (blockIdx.x < half) ? sa : sb;
    bf16* d = (blockIdx.x < half) ? da : db;
    int bid = (blockIdx.x < half) ? blockIdx.x : blockIdx.x - half;
    for (int i = bid * 256 + threadIdx.x; i < n; i += half * 256) {
        float v = f ? ((const float*)s)[i] : (float)((const bf16*)s)[i];
        d[i] = f2b(v);
    }
}

struct VecPack { const void* src[14]; int n[14]; };
__global__ __launch_bounds__(256) void convert_vecs(
    VecPack vp, bf16* __restrict__ dst, const int* __restrict__ flag)
{
    int v = blockIdx.x;
    int f = *flag;
    const void* s = vp.src[v];
    int n = vp.n[v];
    bf16* d = dst + (size_t)v * 4096;
    for (int i = threadIdx.x; i < n; i += 256) {
        float x = f ? ((const float*)s)[i] : (float)((const bf16*)s)[i];
        d[i] = f2b(x);
    }
}

// ---------------------------------------------------------------------------
// GEMM: C[M,N] = A[M,K] @ Bt[n][k]. MT x 128 tile, BK=64, 4 waves.
// global_load_lds w=16 into XOR-swizzled LDS (R6: zero bank conflicts).
// Generalized z-strides: base += z*zs + (z>>2)*zs2 (supports batched local
// attention windows and split-K). bias += z*zsBias.
// EPI: 0 = f32 store (+bias)   1 = bf16 (v+bias)*scale   2 = bf16 gelu(v+bias)
// ---------------------------------------------------------------------------
template <int EPI, int MT>
__global__ __launch_bounds__(256) void gemm_bt(
    const bf16* __restrict__ A0, int lda, int zsA, int zsA2,
    const bf16* __restrict__ B0, int ldb, int zsB, int zsB2,
    void* __restrict__ C0, int ldc, int zsC, int zsC2,
    const bf16* __restrict__ bias, int zsBias, float scale, int K)
{
    constexpr int IFR = MT / 32;
    __shared__ __align__(16) bf16 As[MT * 64];
    __shared__ __align__(16) bf16 Bs[128 * 64];
    const int z = blockIdx.z;
    const bf16* A  = A0 + (size_t)z * zsA + (size_t)(z >> 2) * zsA2;
    const bf16* Bt = B0 + (size_t)z * zsB + (size_t)(z >> 2) * zsB2;
    const size_t cbase = (size_t)z * zsC + (size_t)(z >> 2) * zsC2;
    if (bias) bias += (size_t)z * zsBias;
    const int tid  = threadIdx.x;
    const int lane = tid & 63, wave = tid >> 6;
    const int quad = lane >> 4, l16 = lane & 15;
    const size_t tm = (size_t)blockIdx.y * MT, tn = (size_t)blockIdx.x * 128;
    const int wm = (wave >> 1) * (MT / 2), wn = (wave & 1) * 64;
    const int srow = lane >> 3;
    const int scol = ((lane & 7) ^ srow) * 8;

    f32x4 acc[IFR][4];
    const f32x4 zro = {0.f, 0.f, 0.f, 0.f};
    #pragma unroll
    for (int i = 0; i < IFR; ++i)
        #pragma unroll
        for (int j = 0; j < 4; ++j) acc[i][j] = zro;

    const int swzA = l16 & 7;
    for (int k0 = 0; k0 < K; k0 += 64) {
        #pragma unroll
        for (int i = 0; i < IFR; ++i) {
            int chunk = (wave * IFR + i) * 64;
            int row = (chunk >> 3) + srow;
            gl_lds16(A + (tm + row) * (size_t)lda + k0 + scol, As + (size_t)chunk * 8);
        }
        #pragma unroll
        for (int i = 0; i < 4; ++i) {
            int chunk = (wave * 4 + i) * 64;
            int row = (chunk >> 3) + srow;
            gl_lds16(Bt + (tn + row) * (size_t)ldb + k0 + scol, Bs + (size_t)chunk * 8);
        }
        __syncthreads();
        #pragma unroll
        for (int kk = 0; kk < 2; ++kk) {
            bf16x8 af[IFR], bfr[4];
            #pragma unroll
            for (int i = 0; i < IFR; ++i) {
                int row = wm + i * 16 + l16;
                af[i] = *(const bf16x8*)(const void*)&As[(row * 8 + ((kk*4 + quad) ^ swzA)) * 8];
            }
            #pragma unroll
            for (int j = 0; j < 4; ++j) {
                int row = wn + j * 16 + l16;
                bfr[j] = *(const bf16x8*)(const void*)&Bs[(row * 8 + ((kk*4 + quad) ^ swzA)) * 8];
            }
            #pragma unroll
            for (int i = 0; i < IFR; ++i)
                #pragma unroll
                for (int j = 0; j < 4; ++j)
                    acc[i][j] = __builtin_amdgcn_mfma_f32_16x16x32_bf16(
                        af[i], bfr[j], acc[i][j], 0, 0, 0);
        }
        __syncthreads();
    }

    float* Cf = (float*)C0;
    bf16*  Cb = (bf16*)C0;
    #pragma unroll
    for (int i = 0; i < IFR; ++i) {
        #pragma unroll
        for (int j = 0; j < 4; ++j) {
            size_t col = tn + wn + j*16 + l16;
            float bb = bias ? b2f(bias[col]) : 0.f;
            #pragma unroll
            for (int r = 0; r < 4; ++r) {
                size_t row = tm + wm + i*16 + quad*4 + r;
                float v = acc[i][j][r] + bb;
                size_t off = cbase + row * (size_t)ldc + col;
                if (EPI == 0) {
                    Cf[off] = v;
                } else if (EPI == 1) {
                    Cb[off] = f2b(v * scale);
                } else {
                    float g = 0.5f * v * (1.f + tanhf(0.7978845608028654f *
                                  (v + 0.044715f * v * v * v)));
                    Cb[off] = f2b(g);
                }
            }
        }
    }
}

// ---------------------------------------------------------------------------
// dtype-branching transpose for raw weight inputs -> bf16 transposed
// ---------------------------------------------------------------------------
__global__ void transpose_any(const void* __restrict__ in, int R, int C,
                              unsigned short* __restrict__ out, int ldo,
                              const int* __restrict__ flag)
{
    __shared__ unsigned short t[32][33];
    int f = *flag;
    int c0 = blockIdx.x * 32, r0 = blockIdx.y * 32;
    int tx = threadIdx.x, ty = threadIdx.y;
    for (int i = ty; i < 32; i += 8) {
        size_t idx = (size_t)(r0 + i) * C + c0 + tx;
        bf16 v = f ? f2b(((const float*)in)[idx]) : ((const bf16*)in)[idx];
        t[i][tx] = *(unsigned short*)&v;
    }
    __syncthreads();
    for (int i = ty; i < 32; i += 8)
        out[(size_t)(c0 + i) * ldo + r0 + tx] = t[tx][i];
}

// videoT [b][2048][1024] -> VTpad [b][1024][512 + 2048] (col offset 512), z=b
__global__ void transpose_vt(const unsigned short* __restrict__ in,
                             unsigned short* __restrict__ out)
{
    __shared__ unsigned short t[32][33];
    int b = blockIdx.z;
    const unsigned short* src = in + (size_t)b * 2048 * 1024;
    unsigned short* dst = out + (size_t)b * 1024 * 2560;
    int c0 = blockIdx.x * 32, r0 = blockIdx.y * 32;
    int tx = threadIdx.x, ty = threadIdx.y;
    for (int i = ty; i < 32; i += 8)
        t[i][tx] = src[(size_t)(r0 + i) * 1024 + c0 + tx];
    __syncthreads();
    for (int i = ty; i < 32; i += 8)
        dst[(size_t)(c0 + i) * 2560 + 512 + r0 + tx] = t[tx][i];
}

// ---------------------------------------------------------------------------
// V transpose into per-head Vt[bh][64][2048] bf16.
// ---------------------------------------------------------------------------
__global__ void transpose_v(const float* __restrict__ qkv, bf16* __restrict__ Vt)
{
    __shared__ float t[32][33];
    int bh = blockIdx.z, b = bh >> 3, h = bh & 7;
    const float* src = qkv + (size_t)b * 2048 * 1536 + 1024 + h * 64;
    int c0 = blockIdx.x * 32, r0 = blockIdx.y * 32;
    int tx = threadIdx.x, ty = threadIdx.y;
    for (int i = ty; i < 32; i += 8)
        t[i][tx] = src[(size_t)(r0 + i) * 1536 + c0 + tx];
    __syncthreads();
    bf16* dst = Vt + (size_t)bh * 64 * 2048;
    for (int i = ty; i < 32; i += 8)
        dst[(size_t)(c0 + i) * 2048 + r0 + tx] = f2b(t[tx][i]);
}

// ---------------------------------------------------------------------------
// Row LayerNorm: one block per row.
// ---------------------------------------------------------------------------
template <typename Tin>
__global__ __launch_bounds__(256) void ln_rows(
    const Tin* __restrict__ in, int C,
    const bf16* __restrict__ g, const bf16* __restrict__ b,
    bf16* __restrict__ out, float eps)
{
    const int row = blockIdx.x, tid = threadIdx.x;
    const Tin* p = in + (size_t)row * C;
    float s = 0.f, ss = 0.f;
    for (int c = tid; c < C; c += 256) {
        float v = ldval(p[c]);
        s += v; ss += v * v;
    }
    #pragma unroll
    for (int d = 32; d > 0; d >>= 1) { s += __shfl_xor(s, d); ss += __shfl_xor(ss, d); }
    __shared__ float red[2][4];
    int wave = tid >> 6, lane = tid & 63;
    if (lane == 0) { red[0][wave] = s; red[1][wave] = ss; }
    __syncthreads();
    s  = red[0][0] + red[0][1] + red[0][2] + red[0][3];
    ss = red[1][0] + red[1][1] + red[1][2] + red[1][3];
    float mu   = s / C;
    float var  = ss / C - mu * mu;
    float rstd = rsqrtf(var + eps);
    bf16* q = out + (size_t)row * C;
    for (int c = tid; c < C; c += 256) {
        float v = ldval(p[c]);
        q[c] = f2b((v - mu) * rstd * b2f(g[c]) + b2f(b[c]));
    }
}

// both adapter LNs in one launch: rows 0..4095 audio, 4096..8191 video. C=1024.
__global__ __launch_bounds__(256) void ln_rows2(
    const bf16* __restrict__ in,
    const bf16* __restrict__ g0, const bf16* __restrict__ b0,
    const bf16* __restrict__ g1, const bf16* __restrict__ b1,
    bf16* __restrict__ out0, bf16* __restrict__ out1)
{
    const int row = blockIdx.x, tid = threadIdx.x;
    const int sel = row >> 12;
    const bf16* p = in + (size_t)row * 1024;
    const bf16* g = sel ? g1 : g0;
    const bf16* b = sel ? b1 : b0;
    bf16* q = (sel ? out1 + (size_t)(row - 4096) * 1024 : out0 + (size_t)row * 1024);
    float s = 0.f, ss = 0.f;
    for (int c = tid; c < 1024; c += 256) {
        float v = b2f(p[c]);
        s += v; ss += v * v;
    }
    #pragma unroll
    for (int d = 32; d > 0; d >>= 1) { s += __shfl_xor(s, d); ss += __shfl_xor(ss, d); }
    __shared__ float red[2][4];
    int wave = tid >> 6, lane = tid & 63;
    if (lane == 0) { red[0][wave] = s; red[1][wave] = ss; }
    __syncthreads();
    s  = red[0][0] + red[0][1] + red[0][2] + red[0][3];
    ss = red[1][0] + red[1][1] + red[1][2] + red[1][3];
    float mu   = s * (1.f / 1024.f);
    float var  = ss * (1.f / 1024.f) - mu * mu;
    float rstd = rsqrtf(var + 1e-5f);
    for (int c = tid; c < 1024; c += 256) {
        float v = b2f(p[c]);
        q[c] = f2b((v - mu) * rstd * b2f(g[c]) + b2f(b[c]));
    }
}

// ---------------------------------------------------------------------------
// Rotary (reads raw text via flag): qrot = rope(text)*DIM^-0.5 ;
// krotPad[b][512+t] = rope(audio_t).
// ---------------------------------------------------------------------------
__global__ __launch_bounds__(256) void rotary_kernel(
    const void* __restrict__ text, const int* __restrict__ flag,
    const bf16* __restrict__ audioT,
    bf16* __restrict__ qrot, bf16* __restrict__ krotPad)
{
    int row = blockIdx.x;
    int t = row & 2047, b = row >> 11;
    int tid = threadIdx.x;
    int f = *flag;
    const float lg = 9.210340371976184f / 512.f;
    size_t base = (size_t)row * 1024;
    size_t kb = ((size_t)(b * 2560 + 512 + t)) * 1024;
    for (int c = tid; c < 512; c += 256) {
        float invf = __expf(-(float)c * lg);
        float th = (float)t * invf;
        float sn, cs;
        sincosf(th, &sn, &cs);
        float q1 = f ? ((const float*)text)[base + c]
                     : b2f(((const bf16*)text)[base + c]);
        float q2 = f ? ((const float*)text)[base + c + 512]
                     : b2f(((const bf16*)text)[base + c + 512]);
        qrot[base + c]       = f2b((q1 * cs - q2 * sn) * 0.03125f);
        qrot[base + c + 512] = f2b((q2 * cs + q1 * sn) * 0.03125f);
        float k1 = b2f(audioT[base + c]), k2 = b2f(audioT[base + c + 512]);
        krotPad[kb + c]       = f2b(k1 * cs - k2 * sn);
        krotPad[kb + c + 512] = f2b(k2 * cs + k1 * sn);
    }
}

// ---------------------------------------------------------------------------
// Local-attention masked softmax. sim [b][w][512][1024] f32 -> attn bf16.
// ---------------------------------------------------------------------------
__global__ __launch_bounds__(256) void softmax_local(
    const float* __restrict__ sim, bf16* __restrict__ attn)
{
    int i  = blockIdx.x;
    int zz = blockIdx.y;
    int w  = zz & 3;
    int tid = threadIdx.x;
    const float* p = sim + ((size_t)zz * 512 + i) * 1024;
    bf16* q = attn + ((size_t)zz * 512 + i) * 1024;
    int jlo = (w == 0) ? 512 : 0;
    int jhi = 512 + i;
    float m = -1e30f;
    #pragma unroll
    for (int k = 0; k < 4; ++k) {
        int c = tid + k * 256;
        if (c >= jlo && c <= jhi) m = fmaxf(m, p[c]);
    }
    #pragma unroll
    for (int d = 32; d > 0; d >>= 1) m = fmaxf(m, __shfl_xor(m, d));
    __shared__ float red[2][4];
    int wave = tid >> 6, lane = tid & 63;
    if (lane == 0) red[0][wave] = m;
    __syncthreads();
    m = fmaxf(fmaxf(red[0][0], red[0][1]), fmaxf(red[0][2], red[0][3]));
    float pv[4];
    float s = 0.f;
    #pragma unroll
    for (int k = 0; k < 4; ++k) {
        int c = tid + k * 256;
        float e = (c >= jlo && c <= jhi) ? __expf(p[c] - m) : 0.f;
        pv[k] = e; s += e;
    }
    #pragma unroll
    for (int d = 32; d > 0; d >>= 1) s += __shfl_xor(s, d);
    if (lane == 0) red[1][wave] = s;
    __syncthreads();
    s = red[1][0] + red[1][1] + red[1][2] + red[1][3];
    float inv = 1.f / s;
    #pragma unroll
    for (int k = 0; k < 4; ++k) q[tid + k * 256] = f2b(pv[k] * inv);
}

// ---------------------------------------------------------------------------
// pack_qk: RMSNorm q/k from qkv f32 [4096][1536] -> per-head bf16 buffers.
// ---------------------------------------------------------------------------
__global__ __launch_bounds__(256) void pack_qk(
    const float* __restrict__ qkv, bf16* __restrict__ Qp, bf16* __restrict__ Kp,
    const bf16* __restrict__ qn_g, const bf16* __restrict__ kn_g)
{
    int gid  = blockIdx.x * 4 + (threadIdx.x >> 6);
    int lane = threadIdx.x & 63;
    int token = gid >> 4, r = gid & 15, part = r >> 3, h = r & 7;
    const float* p = qkv + (size_t)token * 1536 + part * 512 + h * 64 + lane;
    float v = *p;
    float ss = v * v;
    #pragma unroll
    for (int d = 32; d > 0; d >>= 1) ss += __shfl_xor(ss, d);
    float sc = rsqrtf(ss * (1.f / 64.f) + 1e-6f);
    const bf16* gw = part ? kn_g : qn_g;
    float outv = v * sc * b2f(gw[lane]);
    if (!part) outv *= 0.125f;
    int b = token >> 11, t = token & 2047;
    bf16* dst = (part ? Kp : Qp) + ((size_t)(b * 8 + h) * 2048 + t) * 64 + lane;
    *dst = f2b(outv);
}

// ---------------------------------------------------------------------------
// Key-split MFMA flash attention (causal, D=64). Grid (32 qb, 4, 16 bh).
// ---------------------------------------------------------------------------
__global__ __launch_bounds__(256) void flash_split(
    const bf16* __restrict__ Qp, const bf16* __restrict__ Kp,
    const bf16* __restrict__ Vt, bf16* __restrict__ o,
    float* __restrict__ Opart, float* __restrict__ MLpart)
{
    const int qb = blockIdx.x;
    const int chunk = blockIdx.y;
    const int nch = (qb >> 3) + 1;
    if (chunk >= nch) return;
    __shared__ __align__(16) bf16 Ks[64][72];
    __shared__ __align__(16) bf16 Vs[64][72];
    __shared__ __align__(16) bf16 Ps[4][16][72];
    const int bh = blockIdx.z, b = bh >> 3, h = bh & 7;
    const int qm = qb * 64;
    const int jt0 = chunk * 512;
    const int jt1 = min(jt0 + 512, qm + 64);
    const int tid = threadIdx.x, wave = tid >> 6, lane = tid & 63;
    const int quad = lane >> 4, l16 = lane & 15;
    const bf16* Qg = Qp + (size_t)bh * 2048 * 64;
    const bf16* Kg = Kp + (size_t)bh * 2048 * 64;
    const bf16* Vg = Vt + (size_t)bh * 64 * 2048;

    const int qrow = qm + wave * 16 + l16;
    bf16x8 qa[2];
    qa[0] = *(const bf16x8*)(const void*)(Qg + (size_t)qrow * 64 + quad * 8);
    qa[1] = *(const bf16x8*)(const void*)(Qg + (size_t)qrow * 64 + 32 + quad * 8);

    f32x4 oacc[4];
    const f32x4 zro = {0.f, 0.f, 0.f, 0.f};
    #pragma unroll
    for (int j = 0; j < 4; ++j) oacc[j] = zro;
    float mst[4] = {-1e30f, -1e30f, -1e30f, -1e30f};
    float lst[4] = {0.f, 0.f, 0.f, 0.f};

    const int ldr = tid >> 2, ldc = (tid & 3) * 16;
    for (int jt = jt0; jt < jt1; jt += 64) {
        *(uint4*)(void*)&Ks[ldr][ldc] =
            *(const uint4*)(const void*)(Kg + (size_t)(jt + ldr) * 64 + ldc);
        *(uint4*)(void*)&Ks[ldr][ldc + 8] =
            *(const uint4*)(const void*)(Kg + (size_t)(jt + ldr) * 64 + ldc + 8);
        *(uint4*)(void*)&Vs[ldr][ldc] =
            *(const uint4*)(const void*)(Vg + (size_t)ldr * 2048 + jt + ldc);
        *(uint4*)(void*)&Vs[ldr][ldc + 8] =
            *(const uint4*)(const void*)(Vg + (size_t)ldr * 2048 + jt + ldc + 8);
        __syncthreads();

        f32x4 s[4];
        #pragma unroll
        for (int j = 0; j < 4; ++j) s[j] = zro;
        #pragma unroll
        for (int kk = 0; kk < 2; ++kk) {
            #pragma unroll
            for (int j = 0; j < 4; ++j) {
                bf16x8 kb = *(const bf16x8*)(const void*)&Ks[j*16 + l16][kk*32 + quad*8];
                s[j] = __builtin_amdgcn_mfma_f32_16x16x32_bf16(qa[kk], kb, s[j], 0, 0, 0);
            }
        }

        if (jt + 63 > qm + wave * 16) {
            #pragma unroll
            for (int j = 0; j < 4; ++j) {
                int key = jt + j * 16 + l16;
                #pragma unroll
                for (int r = 0; r < 4; ++r) {
                    int row = qm + wave * 16 + quad * 4 + r;
                    if (key > row) s[j][r] = -1e30f;
                }
            }
        }

        f32x4 tmax = s[0];
        #pragma unroll
        for (int j = 1; j < 4; ++j)
            #pragma unroll
            for (int r = 0; r < 4; ++r) tmax[r] = fmaxf(tmax[r], s[j][r]);
        #pragma unroll
        for (int r = 0; r < 4; ++r) {
            float tv = tmax[r];
            #pragma unroll
            for (int d = 1; d < 16; d <<= 1) tv = fmaxf(tv, __shfl_xor(tv, d));
            tmax[r] = tv;
        }
        float scl[4];
        #pragma unroll
        for (int r = 0; r < 4; ++r) {
            float mn = fmaxf(mst[r], tmax[r]);
            scl[r] = __expf(mst[r] - mn);
            mst[r] = mn;
        }
        f32x4 psum = zro;
        #pragma unroll
        for (int j = 0; j < 4; ++j)
            #pragma unroll
            for (int r = 0; r < 4; ++r) {
                float e = __expf(s[j][r] - mst[r]);
                s[j][r] = e;
                psum[r] += e;
            }
        #pragma unroll
        for (int r = 0; r < 4; ++r) {
            float tv = psum[r];
            #pragma unroll
            for (int d = 1; d < 16; d <<= 1) tv += __shfl_xor(tv, d);
            lst[r] = lst[r] * scl[r] + tv;
        }
        #pragma unroll
        for (int j = 0; j < 4; ++j)
            #pragma unroll
            for (int r = 0; r < 4; ++r) oacc[j][r] *= scl[r];

        #pragma unroll
        for (int j = 0; j < 4; ++j)
            #pragma unroll
            for (int r = 0; r < 4; ++r)
                Ps[wave][quad*4 + r][j*16 + l16] = f2b(s[j][r]);
        bf16x8 pa[2];
        pa[0] = *(const bf16x8*)(const void*)&Ps[wave][l16][quad*8];
        pa[1] = *(const bf16x8*)(const void*)&Ps[wave][l16][32 + quad*8];

        #pragma unroll
        for (int kk = 0; kk < 2; ++kk) {
            #pragma unroll
            for (int j = 0; j < 4; ++j) {
                bf16x8 vb = *(const bf16x8*)(const void*)&Vs[j*16 + l16][kk*32 + quad*8];
                oacc[j] = __builtin_amdgcn_mfma_f32_16x16x32_bf16(pa[kk], vb, oacc[j], 0, 0, 0);
            }
        }
        __syncthreads();
    }

    if (nch == 1) {
        #pragma unroll
        for (int j = 0; j < 4; ++j) {
            #pragma unroll
            for (int r = 0; r < 4; ++r) {
                int t = qm + wave * 16 + quad * 4 + r;
                o[((size_t)(b * 2048 + t)) * 512 + h * 64 + j * 16 + l16] =
                    f2b(oacc[j][r] / lst[r]);
            }
        }
    } else {
        int pidx = (bh * 32 + qb) * 4 + chunk;
        float* Od = Opart + (size_t)pidx * 4096;
        #pragma unroll
        for (int j = 0; j < 4; ++j)
            #pragma unroll
            for (int r = 0; r < 4; ++r) {
                int row = wave * 16 + quad * 4 + r;
                Od[row * 64 + j * 16 + l16] = oacc[j][r];
            }
        if (l16 == 0) {
            #pragma unroll
            for (int r = 0; r < 4; ++r) {
                int row = wave * 16 + quad * 4 + r;
                MLpart[(size_t)pidx * 128 + row]      = mst[r];
                MLpart[(size_t)pidx * 128 + 64 + row] = lst[r];
            }
        }
    }
}

// ---------------------------------------------------------------------------
// Merge key-split partials for qb >= 8. Grid (24, 16), 256 thr.
// ---------------------------------------------------------------------------
__global__ __launch_bounds__(256) void flash_combine(
    const float* __restrict__ Opart, const float* __restrict__ MLpart,
    bf16* __restrict__ o)
{
    int qb = blockIdx.x + 8;
    int bh = blockIdx.y, b = bh >> 3, h = bh & 7;
    int nch = (qb >> 3) + 1;
    int row = threadIdx.x >> 2;
    int d0 = (threadIdx.x & 3) * 16;
    int base = (bh * 32 + qb) * 4;
    float m[4], l[4], w[4];
    float mstar = -1e30f;
    for (int c = 0; c < nch; ++c) {
        m[c] = MLpart[(size_t)(base + c) * 128 + row];
        l[c] = MLpart[(size_t)(base + c) * 128 + 64 + row];
        mstar = fmaxf(mstar, m[c]);
    }
    float lstar = 0.f;
    for (int c = 0; c < nch; ++c) {
        w[c] = __expf(m[c] - mstar);
        lstar += l[c] * w[c];
    }
    float inv = 1.f / lstar;
    int t = qb * 64 + row;
    bf16* op = o + ((size_t)(b * 2048 + t)) * 512 + h * 64 + d0;
    #pragma unroll 4
    for (int dd = 0; dd < 16; ++dd) {
        float acc = 0.f;
        for (int c = 0; c < nch; ++c)
            acc += Opart[(size_t)(base + c) * 4096 + row * 64 + d0 + dd] * w[c];
        op[dd] = f2b(acc * inv);
    }
}

// ---------------------------------------------------------------------------
// FF2 split-K merge + bias + residual: out f32 = p0+p1+b2+x2. 4M elements.
// ---------------------------------------------------------------------------
__global__ __launch_bounds__(256) void combine_ff2(
    const float* __restrict__ p0, const float* __restrict__ p1,
    const bf16* __restrict__ x2, const bf16* __restrict__ b2,
    float* __restrict__ out)
{
    int i4 = (blockIdx.x * 256 + threadIdx.x) * 4;
    #pragma unroll
    for (int k = 0; k < 4; ++k) {
        int i = i4 + k;
        out[i] = p0[i] + p1[i] + b2f(x2[i]) + b2f(b2[i & 1023]);
    }
}

// ---------------------------------------------------------------------------
static void launch_gemm(int epi, hipStream_t s,
                        const bf16* A, int lda, int zsA, int zsA2,
                        const bf16* Bt, int ldb, int zsB, int zsB2,
                        void* C, int ldc, int zsC, int zsC2,
                        const bf16* bias, int zsBias, float scale,
                        int M, int N, int K, int nz)
{
    bool mt64 = ((M >> 7) * (N >> 7) * nz) <= 512;
    dim3 blk(256);
    if (mt64) {
        dim3 g(N / 128, M / 64, nz);
        switch (epi) {
        case 0: gemm_bt<0,64><<<g, blk, 0, s>>>(A, lda, zsA, zsA2, Bt, ldb, zsB, zsB2, C, ldc, zsC, zsC2, bias, zsBias, scale, K); break;
        case 1: gemm_bt<1,64><<<g, blk, 0, s>>>(A, lda, zsA, zsA2, Bt, ldb, zsB, zsB2, C, ldc, zsC, zsC2, bias, zsBias, scale, K); break;
        default: gemm_bt<2,64><<<g, blk, 0, s>>>(A, lda, zsA, zsA2, Bt, ldb, zsB, zsB2, C, ldc, zsC, zsC2, bias, zsBias, scale, K); break;
        }
    } else {
        dim3 g(N / 128, M / 128, nz);
        switch (epi) {
        case 0: gemm_bt<0,128><<<g, blk, 0, s>>>(A, lda, zsA, zsA2, Bt, ldb, zsB, zsB2, C, ldc, zsC, zsC2, bias, zsBias, scale, K); break;
        case 1: gemm_bt<1,128><<<g, blk, 0, s>>>(A, lda, zsA, zsA2, Bt, ldb, zsB, zsB2, C, ldc, zsC, zsC2, bias, zsBias, scale, K); break;
        default: gemm_bt<2,128><<<g, blk, 0, s>>>(A, lda, zsA, zsA2, Bt, ldb, zsB, zsB2, C, ldc, zsC, zsC2, bias, zsBias, scale, K); break;
        }
    }
}

extern "C" void kernel_launch(void* const* d_in, const int* in_sizes, int n_in,
                              void* d_out, int out_size, void* d_ws, size_t ws_size,
                              hipStream_t stream)
{
    const void* text  = d_in[0];
    const void* audio = d_in[1];
    const void* video = d_in[2];
    const void* Wa    = d_in[3];
    const void* ba    = d_in[4];
    const void* lna_g = d_in[5];
    const void* lna_b = d_in[6];
    const void* Wvid  = d_in[7];
    const void* bvid  = d_in[8];
    const void* lnv_g = d_in[9];
    const void* lnv_b = d_in[10];
    const void* ln1_g = d_in[11];
    const void* ln1_b = d_in[12];
    const void* Wq    = d_in[13];
    const void* Wkv   = d_in[14];
    const void* qn_g  = d_in[15];
    const void* kn_g  = d_in[16];
    const void* Wo    = d_in[17];
    const void* W1    = d_in[18];
    const void* b1    = d_in[19];
    const void* ln2_g = d_in[20];
    const void* ln2_b = d_in[21];
    const void* W2    = d_in[22];
    const void* b2    = d_in[23];

    char* ws = (char*)d_ws;
    size_t off = 0;
    auto alloc = [&](size_t bytes) -> char* {
        char* p = ws + off;
        off += (bytes + 255) & ~(size_t)255;
        return p;
    };
    const size_t MB = 1024 * 1024;
    int*  flag  = (int*)alloc(256);
    bf16* vecs  = (bf16*)alloc(14 * 4096 * 2);
    bf16* WqkvT = (bf16*)alloc((size_t)1536 * 1024 * 2);
    bf16* WoT   = (bf16*)alloc((size_t)1024 * 512 * 2);
    bf16* W1T   = (bf16*)alloc((size_t)4096 * 1024 * 2);
    bf16* W2T   = (bf16*)alloc((size_t)1024 * 4096 * 2);
    char* regionIn = alloc(24 * MB);   // audioC,videoC -> qkvF -> Opart/p0
    char* region2  = alloc(32 * MB);   // tmp2/tmpF/xF -> g
    char* regionH  = alloc(8 * MB);    // audioT -> h
    char* regionX  = alloc(8 * MB);    // videoT -> x2
    char* regionO  = alloc(4 * MB);    // WaT,WvT -> o
    bf16* qrot    = (bf16*)alloc((size_t)4096 * 1024 * 2);
    bf16* krotPad = (bf16*)alloc((size_t)2 * 2560 * 1024 * 2);
    bf16* VTpad   = (bf16*)alloc((size_t)2 * 1024 * 2560 * 2);
    bf16* attn    = (bf16*)alloc((size_t)8 * 512 * 1024 * 2);

    bf16*  audioC = (bf16*)regionIn;
    bf16*  videoC = audioC + (size_t)4096 * 1024;
    float* qkvF   = (float*)regionIn;
    bf16*  tmp2   = (bf16*)region2;          // adapter GEMM out (2 x 4096x1024 bf16)
    float* tmpF   = (float*)region2;         // sim scores f32
    float* xF     = (float*)(region2 + 16 * MB);
    bf16*  g      = (bf16*)region2;
    bf16*  audioT = (bf16*)regionH;
    bf16*  h      = (bf16*)regionH;
    bf16*  videoT = (bf16*)regionX;
    bf16*  x2     = (bf16*)regionX;
    bf16*  WaT    = (bf16*)regionO;
    bf16*  WvT    = WaT + (size_t)1024 * 1024;
    bf16*  o      = (bf16*)regionO;
    bf16*  Qp     = qrot;
    bf16*  Kp     = krotPad;
    bf16*  Vth    = attn;
    // flash partials span regionIn+region2 (both dead at that point)
    float* Opart  = (float*)regionIn;
    float* MLpart = Opart + (size_t)16 * 32 * 4 * 4096;
    // FF2 split-K partials (dead regions at FF2 time)
    float* p0     = (float*)regionIn;        // 16 MB of 24
    float* p1     = (float*)VTpad;           // VTpad+attn contiguous 18 MB

    bf16* baC   = vecs + 0 * 4096;
    bf16* bvidC = vecs + 1 * 4096;
    bf16* lnagC = vecs + 2 * 4096;
    bf16* lnabC = vecs + 3 * 4096;
    bf16* lnvgC = vecs + 4 * 4096;
    bf16* lnvbC = vecs + 5 * 4096;
    bf16* ln1gC = vecs + 6 * 4096;
    bf16* ln1bC = vecs + 7 * 4096;
    bf16* qngC  = vecs + 8 * 4096;
    bf16* kngC  = vecs + 9 * 4096;
    bf16* b1C   = vecs + 10 * 4096;
    bf16* ln2gC = vecs + 11 * 4096;
    bf16* ln2bC = vecs + 12 * 4096;
    bf16* b2C   = vecs + 13 * 4096;

    // 1) dtype flag
    detect_dtype<<<1, 64, 0, stream>>>((const unsigned short*)text, flag);

    // 2) canonicalize audio+video (one launch) + small vectors
    const int NTOK = 4096 * 1024;
    convert2<<<4096, 256, 0, stream>>>(audio, video, audioC, videoC, NTOK, flag);
    VecPack vp;
    const void* vsrc[14] = {ba, bvid, lna_g, lna_b, lnv_g, lnv_b, ln1_g, ln1_b,
                            qn_g, kn_g, b1, ln2_g, ln2_b, b2};
    int vn[14] = {1024, 1024, 1024, 1024, 1024, 1024, 1024, 1024,
                  64, 64, 4096, 4096, 4096, 1024};
    for (int i = 0; i < 14; ++i) { vp.src[i] = vsrc[i]; vp.n[i] = vn[i]; }
    convert_vecs<<<14, 256, 0, stream>>>(vp, vecs, flag);

    // 3) weight transposes
    dim3 tb(32, 8);
    transpose_any<<<dim3(32, 32), tb, 0, stream>>>(Wa, 1024, 1024, (unsigned short*)WaT, 1024, flag);
    transpose_any<<<dim3(32, 32), tb, 0, stream>>>(Wvid, 1024, 1024, (unsigned short*)WvT, 1024, flag);
    transpose_any<<<dim3(16, 32), tb, 0, stream>>>(Wq, 1024, 512, (unsigned short*)WqkvT, 1024, flag);
    transpose_any<<<dim3(32, 32), tb, 0, stream>>>(Wkv, 1024, 1024, (unsigned short*)(WqkvT + (size_t)512 * 1024), 1024, flag);
    transpose_any<<<dim3(32, 16), tb, 0, stream>>>(Wo, 512, 1024, (unsigned short*)WoT, 512, flag);
    transpose_any<<<dim3(128, 32), tb, 0, stream>>>(W1, 1024, 4096, (unsigned short*)W1T, 1024, flag);
    transpose_any<<<dim3(32, 128), tb, 0, stream>>>(W2, 4096, 1024, (unsigned short*)W2T, 4096, flag);

    // 4) adapters: one batched GEMM (nz=2, bf16 out w/ bias) + merged LN
    launch_gemm(1, stream, audioC, 1024, 4096*1024, 0, WaT, 1024, 1024*1024, 0,
                tmp2, 1024, 4096*1024, 0, baC, 4096, 1.f, 4096, 1024, 1024, 2);
    ln_rows2<<<8192, 256, 0, stream>>>(tmp2, lnagC, lnabC, lnvgC, lnvbC, audioT, videoT);

    // 5) pads, rotary (raw text), batched VTpad transpose
    hipMemsetAsync(krotPad, 0, (size_t)2 * 2560 * 1024 * 2, stream);
    hipMemsetAsync(VTpad, 0, (size_t)2 * 1024 * 2560 * 2, stream);
    rotary_kernel<<<4096, 256, 0, stream>>>(text, flag, audioT, qrot, krotPad);
    transpose_vt<<<dim3(32, 64, 2), tb, 0, stream>>>(
        (const unsigned short*)videoT, (unsigned short*)VTpad);

    // 6) local attention: batched sim (nz=8) -> softmax -> batched @V (nz=8)
    launch_gemm(0, stream, qrot, 1024, 512*1024, 0,
                krotPad, 1024, 512*1024, 512*1024,
                tmpF, 1024, 512*1024, 0, nullptr, 0, 1.f, 512, 1024, 1024, 8);
    softmax_local<<<dim3(512, 8), 256, 0, stream>>>(tmpF, attn);
    launch_gemm(0, stream, attn, 1024, 512*1024, 0,
                VTpad, 2560, 512, 1024*2560 - 2048,
                xF, 1024, 512*1024, 0, nullptr, 0, 1.f, 512, 1024, 1024, 8);

    // 7) ln1 -> qkv -> pack -> V transpose -> key-split flash -> combine
    ln_rows<float><<<4096, 256, 0, stream>>>(xF, 1024, ln1gC, ln1bC, h, 1e-5f);
    launch_gemm(0, stream, h, 1024, 0, 0, WqkvT, 1024, 0, 0,
                qkvF, 1536, 0, 0, nullptr, 0, 1.f, 4096, 1536, 1024, 1);
    pack_qk<<<16384, 256, 0, stream>>>(qkvF, Qp, Kp, qngC, kngC);
    transpose_v<<<dim3(2, 64, 16), tb, 0, stream>>>(qkvF, Vth);
    flash_split<<<dim3(32, 4, 16), 256, 0, stream>>>(Qp, Kp, Vth, o, Opart, MLpart);
    flash_combine<<<dim3(24, 16), 256, 0, stream>>>(Opart, MLpart, o);

    // 8) x2 = 2*(o@Wo) ; g = gelu(x2@W1+b1) ; ln2 ; FF2 split-K + combine
    launch_gemm(1, stream, o, 512, 0, 0, WoT, 512, 0, 0,
                x2, 1024, 0, 0, nullptr, 0, 2.f, 4096, 1024, 512, 1);
    launch_gemm(2, stream, x2, 1024, 0, 0, W1T, 1024, 0, 0,
                g, 4096, 0, 0, b1C, 0, 1.f, 4096, 4096, 1024, 1);
    ln_rows<bf16><<<4096, 256, 0, stream>>>(g, 4096, ln2gC, ln2bC, g, 1e-5f);
    launch_gemm(0, stream, g, 4096, 2048, 0, W2T, 4096, 2048, 0,
                p0, 1024, (int)(p1 - p0), 0, nullptr, 0, 1.f, 4096, 1024, 2048, 2);
    combine_ff2<<<4096, 256, 0, stream>>>(p0, p1, x2, b2C, (float*)d_out);

    (void)in_sizes; (void)n_in; (void)out_size; (void)ws_size;
}